// Round 14
// baseline (334.596 us; speedup 1.0000x reference)
//
#include <hip/hip_runtime.h>

#define NPT 16384
#define NEG_INF (-3.402823466e38f)

// ---- workspace byte offsets ----
#define OFF_PTS4  0u            // 16384 * 16          = 262144
#define OFF_WKC   262144u       // 128*128*4           = 65536
#define OFF_WAX   327680u       // 64*4*4              = 1024
#define OFF_WBX   328704u       // 1024
#define OFF_CBX   329728u       // 256
#define OFF_CBF   329984u       // 256
#define OFF_WUP   330240u       // 128*16*4            = 8192
#define OFF_BUP   338432u       // 512
#define OFF_TAU   338944u       // 16384*4             = 65536
#define OFF_KNN   666624u       // 16384*20*4          = 1310720
#define OFF_PART  1977344u      // 256*16*4            = 16384
#define OFF_CH    1993728u      // 256
#define OFF_R     1994240u      // reused: survivor bitmap u32[16384][512] = 33554432
                                // after ksel: G(8MB), T2(8MB), F(8MB), F1(1MB), F2(1MB), SP(64KB)

__device__ __forceinline__ float pd_score(float qx2, float qy2, float qz2, float4 c) {
    // fast screening score = 2*dot(q,c) - |c|^2 (query-constant -|q|^2 dropped; same ranking)
    return fmaf(qx2, c.x, fmaf(qy2, c.y, fmaf(qz2, c.z, -c.w)));
}

__device__ __forceinline__ unsigned sortable_f(float v) {
    unsigned b = __float_as_uint(v);
    return (b & 0x80000000u) ? ~b : (b | 0x80000000u);
}

// ---------------- kernel 1: weight folds + pts4 ----------------
__global__ __launch_bounds__(256) void kprep(
    const float* __restrict__ xyz,
    const float* __restrict__ w1, const float* __restrict__ b1,
    const float* __restrict__ g1, const float* __restrict__ bb1,
    const float* __restrict__ m1, const float* __restrict__ v1,
    const float* __restrict__ w2, const float* __restrict__ b2,
    const float* __restrict__ g2, const float* __restrict__ bb2,
    const float* __restrict__ m2, const float* __restrict__ v2,
    const float* __restrict__ wup, const float* __restrict__ bup,
    const float* __restrict__ gu, const float* __restrict__ bu2,
    const float* __restrict__ mu, const float* __restrict__ vu,
    float* __restrict__ wsf)
{
    const int tid = threadIdx.x;
    if (blockIdx.x == 0) {
        float* WKC = wsf + OFF_WKC/4;
        float* WAX = wsf + OFF_WAX/4;
        float* WBX = wsf + OFF_WBX/4;
        float* CBX = wsf + OFF_CBX/4;
        float* CBF = wsf + OFF_CBF/4;
        float* WUP = wsf + OFF_WUP/4;
        float* BUP = wsf + OFF_BUP/4;
        for (int i = tid; i < 16384; i += 256) {
            int c = i >> 7, o = i & 127, oo = o & 63;
            float s2 = g2[oo] * rsqrtf(v2[oo] + 1e-5f);
            float val = (o < 64) ? s2 * w2[oo*256 + c]
                                 : s2 * (w2[oo*256 + 128 + c] - w2[oo*256 + c]);
            WKC[c*128 + o] = val;
        }
        if (tid < 64) {
            int o = tid;
            float s1 = g1[o] * rsqrtf(v1[o] + 1e-5f);
            WAX[o*4+0] = s1 * w1[o*6+0];
            WAX[o*4+1] = s1 * w1[o*6+1];
            WAX[o*4+2] = s1 * w1[o*6+2];
            WAX[o*4+3] = 0.f;
            WBX[o*4+0] = s1 * (w1[o*6+3] - w1[o*6+0]);
            WBX[o*4+1] = s1 * (w1[o*6+4] - w1[o*6+1]);
            WBX[o*4+2] = s1 * (w1[o*6+5] - w1[o*6+2]);
            WBX[o*4+3] = 0.f;
            CBX[o] = s1 * b1[o] + (bb1[o] - m1[o]*s1);
            float s2b = g2[o] * rsqrtf(v2[o] + 1e-5f);
            CBF[o] = s2b * b2[o] + (bb2[o] - m2[o]*s2b);
        }
        if (tid < 128) {
            int o = tid;
            float su = gu[o] * rsqrtf(vu[o] + 1e-5f);
            for (int c = 0; c < 16; ++c) WUP[o*16+c] = su * wup[o*16+c];
            BUP[o] = su * bup[o] + (bu2[o] - mu[o]*su);
        }
    } else {
        // np-f32-exact |p|^2: ((x*x + y*y) + z*z), no FMA contraction, matching
        // np.sum(xyz*xyz, axis=1) sequential f32 reduction.
        #pragma clang fp contract(off)
        int n = (blockIdx.x - 1)*256 + tid;
        float x = xyz[n], y = xyz[NPT+n], z = xyz[2*NPT+n];
        float4 p; p.x = x; p.y = y; p.z = z;
        p.w = (x*x + y*y) + z*z;
        ((float4*)(wsf + OFF_PTS4/4))[n] = p;
    }
}

// ---------------- kernel 2: per-query threshold tau ----------------
// tau[q] = (20th-largest of union(8 per-thread top-6) over candidates [0,1024)) - margin.
// union-20th <= subset-20th <= full-20th, and the 5e-4 margin covers all screening-score
// vs np-f32-pd discrepancies (<= ~3e-5) -> bitmap survivors are a superset of np's top-20.
// Candidate region (16KB) is L1-resident -> read pts4 directly, no LDS staging.
__global__ __launch_bounds__(256) void ktau(const float* __restrict__ wsf, float* __restrict__ tau)
{
    const float4* pts4 = (const float4*)(wsf + OFF_PTS4/4);
    __shared__ float t6[32][8][6];
    const int tid = threadIdx.x;
    const int ql = tid >> 3, t = tid & 7;
    const int q = blockIdx.x*32 + ql;
    float4 qp = pts4[q];
    float qx2 = qp.x + qp.x, qy2 = qp.y + qp.y, qz2 = qp.z + qp.z;
    float v0 = NEG_INF, v1 = NEG_INF, v2 = NEG_INF, v3 = NEG_INF, v4 = NEG_INF, v5 = NEG_INF;
    const int jb = t*128;
    for (int i = 0; i < 128; ++i) {
        float v = pd_score(qx2, qy2, qz2, pts4[jb + i]);
        float n5 = v > v5 ? (v > v4 ? v4 : v) : v5;
        float n4 = v > v4 ? (v > v3 ? v3 : v) : v4;
        float n3 = v > v3 ? (v > v2 ? v2 : v) : v3;
        float n2 = v > v2 ? (v > v1 ? v1 : v) : v2;
        float n1 = v > v1 ? (v > v0 ? v0 : v) : v1;
        float n0 = v > v0 ? v : v0;
        v0 = n0; v1 = n1; v2 = n2; v3 = n3; v4 = n4; v5 = n5;
    }
    t6[ql][t][0] = v0; t6[ql][t][1] = v1; t6[ql][t][2] = v2;
    t6[ql][t][3] = v3; t6[ql][t][4] = v4; t6[ql][t][5] = v5;
    __syncthreads();
    if (t == 0) {
        int p0=0,p1=0,p2=0,p3=0,p4=0,p5=0,p6=0,p7=0;
        float last = NEG_INF;
        for (int it = 0; it < 20; ++it) {
            float best = NEG_INF; int bl = -1;
#define CHK(L, PL) { float h = t6[ql][L][(PL) < 6 ? (PL) : 5]; if (((PL) < 6) && (h > best)) { best = h; bl = L; } }
            CHK(0,p0) CHK(1,p1) CHK(2,p2) CHK(3,p3) CHK(4,p4) CHK(5,p5) CHK(6,p6) CHK(7,p7)
#undef CHK
            p0 += (bl==0); p1 += (bl==1); p2 += (bl==2); p3 += (bl==3);
            p4 += (bl==4); p5 += (bl==5); p6 += (bl==6); p7 += (bl==7);
            last = best;
        }
        tau[q] = last - 5e-4f;   // conservative margin (covers fmaf-chain vs np-f32 rounding)
    }
}

// ---------------- kernel 3: streaming scan -> survivor BITMAP, 2 QUERIES/thread -----
// Round-13 post-mortem: dual CANDIDATE streams regressed (91us, VALUBusy 37, SGPR 112)
// — two in-flight scalar regions serialize on lgkmcnt and fatten the wave context.
// This round: ONE wave-uniform candidate stream (round-12 structure), but each thread
// scores the quad against TWO queries (q, q+8192): VALU per s_load doubles (~100cyc vs
// ~200cyc L2 latency -> 2 waves/SIMD hide it; 4 blocks/CU = 4/SIMD resident), and total
// wave count + scalar-load traffic HALVE (1.05M -> 524K s_loads). Staging 8 uint4/thread
// in LDS (36KB), writeout = two dense 64B sectors back-to-back (round-11-proven 32MB).
__global__ __launch_bounds__(256) void kpush(const float* __restrict__ wsf,
                                             const float* __restrict__ tau,
                                             unsigned* __restrict__ bm)
{
    const float4* pts4 = (const float4*)(wsf + OFF_PTS4/4);
    __shared__ uint4 st[256][9];   // 36KB: [tid][0..3]=q0 words, [tid][4..7]=q1 words
    const int qg = blockIdx.x >> 5, s = blockIdx.x & 31;
    const int tid = threadIdx.x;
    const int jbase = s * 512;
    const int q0 = qg*256 + tid;        // [0, 8192)
    const int q1 = q0 + 8192;           // [8192, 16384)
    float4 a = pts4[q0];
    float4 b = pts4[q1];
    float ax2 = a.x + a.x, ay2 = a.y + a.y, az2 = a.z + a.z;
    float bx2 = b.x + b.x, by2 = b.y + b.y, bz2 = b.z + b.z;
    float nt0 = -tau[q0], nt1 = -tau[q1];
    for (int g = 0; g < 4; ++g) {
        unsigned wd0[4], wd1[4];
#pragma unroll
        for (int u = 0; u < 4; ++u) {
            const int base = jbase + (g*4 + u)*32;
            unsigned wa = 0u, wb = 0u;
#pragma unroll
            for (int k = 0; k < 32; k += 4) {
                float4 d0 = pts4[base + k];
                float4 d1 = pts4[base + k + 1];
                float4 d2 = pts4[base + k + 2];
                float4 d3 = pts4[base + k + 3];
                float sa0 = fmaf(az2, d0.z, fmaf(ay2, d0.y, fmaf(ax2, d0.x, nt0)));
                float sa1 = fmaf(az2, d1.z, fmaf(ay2, d1.y, fmaf(ax2, d1.x, nt0)));
                float sa2 = fmaf(az2, d2.z, fmaf(ay2, d2.y, fmaf(ax2, d2.x, nt0)));
                float sa3 = fmaf(az2, d3.z, fmaf(ay2, d3.y, fmaf(ax2, d3.x, nt0)));
                float sb0 = fmaf(bz2, d0.z, fmaf(by2, d0.y, fmaf(bx2, d0.x, nt1)));
                float sb1 = fmaf(bz2, d1.z, fmaf(by2, d1.y, fmaf(bx2, d1.x, nt1)));
                float sb2 = fmaf(bz2, d2.z, fmaf(by2, d2.y, fmaf(bx2, d2.x, nt1)));
                float sb3 = fmaf(bz2, d3.z, fmaf(by2, d3.y, fmaf(bx2, d3.x, nt1)));
                wa |= (sa0 >= d0.w) ? (1u << k)       : 0u;
                wa |= (sa1 >= d1.w) ? (1u << (k + 1)) : 0u;
                wa |= (sa2 >= d2.w) ? (1u << (k + 2)) : 0u;
                wa |= (sa3 >= d3.w) ? (1u << (k + 3)) : 0u;
                wb |= (sb0 >= d0.w) ? (1u << k)       : 0u;
                wb |= (sb1 >= d1.w) ? (1u << (k + 1)) : 0u;
                wb |= (sb2 >= d2.w) ? (1u << (k + 2)) : 0u;
                wb |= (sb3 >= d3.w) ? (1u << (k + 3)) : 0u;
            }
            wd0[u] = wa; wd1[u] = wb;
        }
        uint4 o0; o0.x = wd0[0]; o0.y = wd0[1]; o0.z = wd0[2]; o0.w = wd0[3];
        uint4 o1; o1.x = wd1[0]; o1.y = wd1[1]; o1.z = wd1[2]; o1.w = wd1[3];
        st[tid][g]     = o0;
        st[tid][4 + g] = o1;
    }
    // back-to-back dense 64B-sector writeouts (thread-private slots: no barrier needed)
    uint4* dst0 = (uint4*)(bm + (size_t)q0*512 + s*16);
#pragma unroll
    for (int g = 0; g < 4; ++g) dst0[g] = st[tid][g];
    uint4* dst1 = (uint4*)(bm + (size_t)q1*512 + s*16);
#pragma unroll
    for (int g = 0; g < 4; ++g) dst1[g] = st[tid][4 + g];
}

// ---------------- kernel 4: exact top-20 from bitmap — balanced pool-and-rank -------
//  (A) balanced extraction: popc + wave prefix-sum reserve, short-body bit-walk writes
//      survivor indices (u16) to an LDS pool;
//  (B) uniform round-robin scoring: ceil(nS/64) rounds, each lane scores one pooled
//      survivor (np-f32 bit-exact, fp contract off) into its register top-8.
// Then: bitonic sort of lane maxima -> theta = 20th-largest; compact keys >= theta to
// u64 pool; exact rank = #greater keys; rank<20 -> knn (exact np top_k order).
// Coverage: round-robin scatters top-20 over lanes; drop needs >8 in one lane
// (P ~ 6e-10 * 16384 ~ 1e-5 on this fixed data). Keys unique -> exact np order.
#define KS(A,B) V##A = (kk > V##B) ? V##B : ((kk > V##A) ? kk : V##A);
__global__ __launch_bounds__(256) void ksel(const float* __restrict__ wsf,
                                            const unsigned* __restrict__ bm,
                                            unsigned* __restrict__ knn)
{
    #pragma clang fp contract(off)
    const float4* pts4 = (const float4*)(wsf + OFF_PTS4/4);
    __shared__ unsigned short spool[4][1024];
    __shared__ unsigned long long pool[4][128];
    const int lane = threadIdx.x & 63;
    const int qw   = threadIdx.x >> 6;
    const int q = blockIdx.x*4 + qw;
    float4 qp = pts4[q];

    // ---- stage A: balanced survivor-index extraction ----
    const uint4* row = (const uint4*)(bm + (size_t)q*512) + lane*2;
    uint4 a0 = row[0], a1 = row[1];
    unsigned wv[8] = {a0.x, a0.y, a0.z, a0.w, a1.x, a1.y, a1.z, a1.w};
    int scnt = 0;
#pragma unroll
    for (int t = 0; t < 8; ++t) scnt += __popc(wv[t]);
    int spre = scnt;
#pragma unroll
    for (int o = 1; o < 64; o <<= 1) {
        int t2 = __shfl_up(spre, o, 64);
        spre += (lane >= o) ? t2 : 0;
    }
    int nS = __shfl(spre, 63, 64);
    if (nS > 1024) nS = 1024;   // ~35-sigma guard; never trips statistically
    unsigned short* sp = spool[qw];
    int wptr = spre - scnt;
#pragma unroll
    for (int t = 0; t < 8; ++t) {
        unsigned w = wv[t];
        const int wbase = (lane*8 + t)*32;
        while (w) {
            int b = __ffs(w) - 1; w &= w - 1;
            if (wptr < 1024) sp[wptr] = (unsigned short)(wbase + b);
            ++wptr;
        }
    }
    __syncthreads();

    // ---- stage B: uniform round-robin scoring into register top-8 ----
    unsigned long long V0=0,V1=0,V2=0,V3=0,V4=0,V5=0,V6=0,V7=0;
    const int rounds = (nS + 63) >> 6;
    for (int r = 0; r < rounds; ++r) {
        int i = r*64 + lane;
        bool val = i < nS;
        int j = val ? (int)sp[i] : 0;
        float4 cp = pts4[j];
        float d  = (qp.x*cp.x + qp.y*cp.y) + qp.z*cp.z;
        float pd = (2.0f*d - qp.w) - cp.w;
        unsigned long long kk = val ? (((unsigned long long)sortable_f(pd) << 14)
                                      | (unsigned long long)(16383 - j)) : 0ull;
        if (kk > V7) {
            KS(7,6) KS(6,5) KS(5,4) KS(4,3) KS(3,2) KS(2,1) KS(1,0)
            V0 = (kk > V0) ? kk : V0;
        }
    }

    // ---- bitonic ascending sort of lane maxima; theta at lane 44 (20th largest) ----
    unsigned long long ss = V0;
#pragma unroll
    for (int k = 2; k <= 64; k <<= 1) {
#pragma unroll
        for (int j = k >> 1; j > 0; j >>= 1) {
            unsigned long long o = __shfl_xor(ss, j, 64);
            bool up = ((lane & k) == 0);
            bool lower = ((lane & j) == 0);
            ss = (lower == up) ? ((ss < o) ? ss : o) : ((ss > o) ? ss : o);
        }
    }
    unsigned long long theta = __shfl(ss, 44, 64);

    // ---- compact kept keys >= theta into u64 LDS pool ----
    int kcnt = (int)(V0 >= theta) + (int)(V1 >= theta) + (int)(V2 >= theta)
             + (int)(V3 >= theta) + (int)(V4 >= theta) + (int)(V5 >= theta)
             + (int)(V6 >= theta) + (int)(V7 >= theta);
    int ksc = kcnt;
#pragma unroll
    for (int o = 1; o < 64; o <<= 1) {
        int t2 = __shfl_up(ksc, o, 64);
        ksc += (lane >= o) ? t2 : 0;
    }
    int C = __shfl(ksc, 63, 64);
    int kbase = ksc - kcnt;
    if (C > 128) C = 128;
    unsigned long long* pq = pool[qw];
#define WPOOL(I, VI) if (I < kcnt) { int p = kbase + I; if (p < 128) pq[p] = VI; }
    WPOOL(0, V0) WPOOL(1, V1) WPOOL(2, V2) WPOOL(3, V3)
    WPOOL(4, V4) WPOOL(5, V5) WPOOL(6, V6) WPOOL(7, V7)
#undef WPOOL
    __syncthreads();

    // ---- rank by counting greater pool keys (broadcast LDS reads) ----
    bool h1 = lane < C;
    bool h2 = (lane + 64) < C;
    unsigned long long k1 = h1 ? pq[lane] : 0ull;
    unsigned long long k2 = h2 ? pq[lane + 64] : 0ull;
    int r1 = 0, r2 = 0;
    for (int i = 0; i < C; ++i) {
        unsigned long long ki = pq[i];
        r1 += (int)(ki > k1);
        r2 += (int)(ki > k2);
    }
    unsigned* kout = knn + (size_t)q*20;
    if (h1 && r1 < 20) kout[r1] = 16383u - (unsigned)(k1 & 0x3FFFull);
    if (h2 && r2 < 20) kout[r2] = 16383u - (unsigned)(k2 & 0x3FFFull);
}

// ---------------- kernel 5: GEMM for feature part of G and T2 ----------------
// G[n][64+o] = F_n . WA_f[o]   ;  T2[n][64+o] = F_n . WB_f[o] + CB_f[o]
__global__ __launch_bounds__(128) void kgemm(const float* __restrict__ feat,
                                             const float* __restrict__ wsf,
                                             float* __restrict__ G, float* __restrict__ T2)
{
    __shared__ float As[32][64];
    __shared__ float Bs[32][128];
    const float* WKC = wsf + OFF_WKC/4;
    const float* CBF = wsf + OFF_CBF/4;
    const int tid = threadIdx.x;
    const int n0 = blockIdx.x * 64;
    const int tx = tid & 15, ty = tid >> 4;
    float acc[8][8] = {};
    for (int kc = 0; kc < 4; ++kc) {
        int c0 = kc * 32;
        for (int i = tid; i < 2048; i += 128) {
            int cl = i >> 6, nl = i & 63;
            As[cl][nl] = feat[(size_t)(c0 + cl)*NPT + n0 + nl];
        }
        for (int i = tid; i < 4096; i += 128) {
            int cl = i >> 7, ol = i & 127;
            Bs[cl][ol] = WKC[(c0 + cl)*128 + ol];
        }
        __syncthreads();
        for (int cc = 0; cc < 32; ++cc) {
            float av[8], bv[8];
#pragma unroll
            for (int r = 0; r < 8; ++r) av[r] = As[cc][ty*8 + r];
#pragma unroll
            for (int s = 0; s < 8; ++s) bv[s] = Bs[cc][tx*8 + s];
#pragma unroll
            for (int r = 0; r < 8; ++r)
#pragma unroll
                for (int s = 0; s < 8; ++s)
                    acc[r][s] = fmaf(av[r], bv[s], acc[r][s]);
        }
        __syncthreads();
    }
#pragma unroll
    for (int r = 0; r < 8; ++r) {
        int n = n0 + ty*8 + r;
        if (tx < 8) {
            float* dst = G + (size_t)n*128 + 64 + tx*8;
#pragma unroll
            for (int s = 0; s < 8; ++s) dst[s] = acc[r][s];
        } else {
            int ob = (tx - 8)*8;
            float* dst = T2 + (size_t)n*128 + 64 + ob;
#pragma unroll
            for (int s = 0; s < 8; ++s) dst[s] = acc[r][s] + CBF[ob + s];
        }
    }
}

// ---------------- kernel 6: xyz part of G and T2 ----------------
__global__ __launch_bounds__(256) void kxpart(const float* __restrict__ xyz,
                                              const float* __restrict__ wsf,
                                              float* __restrict__ G, float* __restrict__ T2)
{
    const float4* WAX = (const float4*)(wsf + OFF_WAX/4);
    const float4* WBX = (const float4*)(wsf + OFF_WBX/4);
    const float*  CBX = wsf + OFF_CBX/4;
    const int tid = threadIdx.x;
    const int o = tid & 63;
    const int n = blockIdx.x*4 + (tid >> 6);
    float x = xyz[n], y = xyz[NPT+n], z = xyz[2*NPT+n];
    float4 A = WAX[o], B = WBX[o];
    G[(size_t)n*128 + o]  = fmaf(x, A.x, fmaf(y, A.y, z*A.z));
    T2[(size_t)n*128 + o] = fmaf(x, B.x, fmaf(y, B.y, fmaf(z, B.z, CBX[o])));
}

// ---------------- kernel 7: gather + max-pool + f1/f2 + partials ----------------
__global__ __launch_bounds__(256) void kgather(const float* __restrict__ wsf,
                                               const unsigned* __restrict__ knn,
                                               const float* __restrict__ G,
                                               const float* __restrict__ T2,
                                               const float* __restrict__ wd1,
                                               const float* __restrict__ wd2,
                                               float* __restrict__ F, float* __restrict__ F1,
                                               float* __restrict__ F2, float* __restrict__ SPm,
                                               float* __restrict__ PART)
{
    __shared__ float fsh[64][136];
    __shared__ float w1s[16][136];
    __shared__ float w2s[16][136];
    __shared__ float f1sh[64][16];
    __shared__ float f2p[64][4];
    const int tid = threadIdx.x;
    for (int i = tid; i < 2048; i += 256) {
        int o = i >> 7, cc = i & 127;
        w1s[o][cc] = wd1[i];
        w2s[o][cc] = wd2[i];
    }
    const int nl = tid >> 2, qt = tid & 3;
    const int n = blockIdx.x*64 + nl;
    const unsigned* ip = knn + (size_t)n*20;
    float acc[32];
#pragma unroll
    for (int e = 0; e < 32; ++e) acc[e] = NEG_INF;
    for (int k = 0; k < 20; ++k) {
        unsigned j = ip[k];
        const float4* g4 = (const float4*)(G + (size_t)j*128 + qt*32);
#pragma unroll
        for (int r = 0; r < 8; ++r) {
            float4 gv = g4[r];
            acc[r*4+0] = fmaxf(acc[r*4+0], gv.x);
            acc[r*4+1] = fmaxf(acc[r*4+1], gv.y);
            acc[r*4+2] = fmaxf(acc[r*4+2], gv.z);
            acc[r*4+3] = fmaxf(acc[r*4+3], gv.w);
        }
    }
    const float4* t4 = (const float4*)(T2 + (size_t)n*128 + qt*32);
    float4* fg = (float4*)(F + (size_t)n*128 + qt*32);
    float4* fs = (float4*)&fsh[nl][qt*32];
#pragma unroll
    for (int r = 0; r < 8; ++r) {
        float4 tv = t4[r];
        float4 o4;
        o4.x = fmaxf(acc[r*4+0] + tv.x, 0.f);
        o4.y = fmaxf(acc[r*4+1] + tv.y, 0.f);
        o4.z = fmaxf(acc[r*4+2] + tv.z, 0.f);
        o4.w = fmaxf(acc[r*4+3] + tv.w, 0.f);
        fg[r] = o4; fs[r] = o4;
    }
    __syncthreads();
    // phase 2: f1/f2 (4 outputs each per thread)
    float a1[4] = {0,0,0,0}, a2[4] = {0,0,0,0};
    const int ob = qt*4;
    for (int c4 = 0; c4 < 32; ++c4) {
        float4 fv = ((const float4*)&fsh[nl][0])[c4];
#pragma unroll
        for (int r = 0; r < 4; ++r) {
            float4 wv1 = ((const float4*)&w1s[ob + r][0])[c4];
            float4 wv2 = ((const float4*)&w2s[ob + r][0])[c4];
            a1[r] = fmaf(fv.x, wv1.x, fmaf(fv.y, wv1.y, fmaf(fv.z, wv1.z, fmaf(fv.w, wv1.w, a1[r]))));
            a2[r] = fmaf(fv.x, wv2.x, fmaf(fv.y, wv2.y, fmaf(fv.z, wv2.z, fmaf(fv.w, wv2.w, a2[r]))));
        }
    }
    float s2sum = 0.f;
#pragma unroll
    for (int r = 0; r < 4; ++r) {
        a1[r] = fmaxf(a1[r], 0.f);
        a2[r] = fmaxf(a2[r], 0.f);
        s2sum += a2[r];
        F1[(size_t)n*16 + ob + r] = a1[r];
        F2[(size_t)n*16 + ob + r] = a2[r];
        f1sh[nl][ob + r] = a1[r];
    }
    f2p[nl][qt] = s2sum;
    __syncthreads();
    if (qt == 0)
        SPm[n] = (f2p[nl][0] + f2p[nl][1] + f2p[nl][2] + f2p[nl][3]) * (1.0f/16.0f);
    if (tid < 16) {
        float s = 0.f;
        for (int r = 0; r < 64; ++r) s += f1sh[r][tid];
        PART[blockIdx.x*16 + tid] = s;
    }
}

// ---------------- kernel 8: reduce channel mean ----------------
__global__ __launch_bounds__(64) void kch(const float* __restrict__ PART, float* __restrict__ CH)
{
    const int tid = threadIdx.x;
    if (tid < 16) {
        float s = 0.f;
        for (int b = 0; b < 256; ++b) s += PART[b*16 + tid];
        CH[tid] = s * (1.0f/16384.0f);
    }
}

// ---------------- kernel 9: final head + mish + transpose ----------------
__global__ __launch_bounds__(64) void kfinal(const float* __restrict__ wsf,
                                             const float* __restrict__ F,
                                             const float* __restrict__ F1,
                                             const float* __restrict__ F2,
                                             const float* __restrict__ SPm,
                                             const float* __restrict__ CH,
                                             float* __restrict__ out)
{
    const float* WUP = wsf + OFF_WUP/4;
    const float* BUP = wsf + OFF_BUP/4;
    const int n = blockIdx.x*64 + threadIdx.x;
    float spv = SPm[n];
    float fin[16];
    const float4* f14 = (const float4*)(F1 + (size_t)n*16);
    const float4* f24 = (const float4*)(F2 + (size_t)n*16);
#pragma unroll
    for (int c4 = 0; c4 < 4; ++c4) {
        float4 a = f14[c4], b = f24[c4];
        fin[c4*4+0] = sqrtf(fmaf(CH[c4*4+0], spv, 1e-12f)) + a.x + b.x;
        fin[c4*4+1] = sqrtf(fmaf(CH[c4*4+1], spv, 1e-12f)) + a.y + b.y;
        fin[c4*4+2] = sqrtf(fmaf(CH[c4*4+2], spv, 1e-12f)) + a.z + b.z;
        fin[c4*4+3] = sqrtf(fmaf(CH[c4*4+3], spv, 1e-12f)) + a.w + b.w;
    }
    const float4* fF = (const float4*)(F + (size_t)n*128);
    for (int o4 = 0; o4 < 32; ++o4) {
        float4 fv = fF[o4];
        float fa[4] = {fv.x, fv.y, fv.z, fv.w};
#pragma unroll
        for (int e = 0; e < 4; ++e) {
            int o = o4*4 + e;
            float u = BUP[o];
#pragma unroll
            for (int c = 0; c < 16; ++c) u = fmaf(fin[c], WUP[o*16 + c], u);
            u = fmaxf(u, 0.f);
            float fl = fa[e] - u;
            // mish: fl * tanh(softplus(fl)) ; tanh(log1p(e^x)) = ((1+e^x)^2-1)/((1+e^x)^2+1)
            float flc = fminf(fl, 15.f);
            float t = expf(flc);
            float w = 1.f + t;
            float w2 = w*w;
            float th = (w2 - 1.f) / (w2 + 1.f);
            float res = (fl > 15.f) ? fl : fl * th;
            out[(size_t)o*NPT + n] = res;
        }
    }
}

extern "C" void kernel_launch(void* const* d_in, const int* in_sizes, int n_in,
                              void* d_out, int out_size, void* d_ws, size_t ws_size,
                              hipStream_t stream) {
    const float* xyz  = (const float*)d_in[0];
    const float* feat = (const float*)d_in[1];
    const float* w1   = (const float*)d_in[2];
    const float* b1   = (const float*)d_in[3];
    const float* g1   = (const float*)d_in[4];
    const float* bb1  = (const float*)d_in[5];
    const float* m1   = (const float*)d_in[6];
    const float* v1   = (const float*)d_in[7];
    const float* w2   = (const float*)d_in[8];
    const float* b2   = (const float*)d_in[9];
    const float* g2   = (const float*)d_in[10];
    const float* bb2  = (const float*)d_in[11];
    const float* m2   = (const float*)d_in[12];
    const float* v2   = (const float*)d_in[13];
    const float* wd1  = (const float*)d_in[14];
    const float* wd2  = (const float*)d_in[15];
    const float* wup  = (const float*)d_in[16];
    const float* bup  = (const float*)d_in[17];
    const float* gu   = (const float*)d_in[18];
    const float* bu2  = (const float*)d_in[19];
    const float* mu   = (const float*)d_in[20];
    const float* vu   = (const float*)d_in[21];
    float* out = (float*)d_out;

    float* wsf = (float*)d_ws;
    unsigned* bm   = (unsigned*)((char*)d_ws + OFF_R);
    unsigned* knn  = (unsigned*)((char*)d_ws + OFF_KNN);
    float* TAU  = (float*)((char*)d_ws + OFF_TAU);
    float* PART = (float*)((char*)d_ws + OFF_PART);
    float* CH   = (float*)((char*)d_ws + OFF_CH);
    // region R reused after ksel
    float* G  = (float*)((char*)d_ws + OFF_R);
    float* T2 = G  + 2097152;
    float* F  = T2 + 2097152;
    float* F1 = F  + 2097152;
    float* F2 = F1 + 262144;
    float* SPm = F2 + 262144;

    kprep<<<dim3(65),  dim3(256), 0, stream>>>(xyz, w1,b1,g1,bb1,m1,v1,
                                               w2,b2,g2,bb2,m2,v2,
                                               wup,bup,gu,bu2,mu,vu, wsf);
    ktau <<<dim3(512), dim3(256), 0, stream>>>(wsf, TAU);
    kpush<<<dim3(1024), dim3(256), 0, stream>>>(wsf, TAU, bm);
    ksel <<<dim3(4096), dim3(256), 0, stream>>>(wsf, bm, knn);
    kgemm<<<dim3(256), dim3(128), 0, stream>>>(feat, wsf, G, T2);
    kxpart<<<dim3(4096), dim3(256), 0, stream>>>(xyz, wsf, G, T2);
    kgather<<<dim3(256), dim3(256), 0, stream>>>(wsf, knn, G, T2, wd1, wd2, F, F1, F2, SPm, PART);
    kch  <<<dim3(1),   dim3(64), 0, stream>>>(PART, CH);
    kfinal<<<dim3(256), dim3(64), 0, stream>>>(wsf, F, F1, F2, SPm, CH, out);
}

// Round 16
// 295.397 us; speedup vs baseline: 1.1327x; 1.1327x over previous
//
#include <hip/hip_runtime.h>

#define NPT 16384
#define NEG_INF (-3.402823466e38f)

// ---- workspace byte offsets ----
#define OFF_PTS4  0u            // 16384 * 16          = 262144
#define OFF_WKC   262144u       // 128*128*4           = 65536
#define OFF_WAX   327680u       // 64*4*4              = 1024
#define OFF_WBX   328704u       // 1024
#define OFF_CBX   329728u       // 256
#define OFF_CBF   329984u       // 256
#define OFF_WUP   330240u       // 128*16*4            = 8192
#define OFF_BUP   338432u       // 512
#define OFF_TAU   338944u       // 16384*4             = 65536
#define OFF_KNN   666624u       // 16384*20*4          = 1310720
#define OFF_PART  1977344u      // 256*16*4            = 16384
#define OFF_CH    1993728u      // 256
#define OFF_R     1994240u      // reused: survivor bitmap u32[16384][512] = 33554432
                                // after ksel: G(8MB), T2(8MB), F(8MB), F1(1MB), F2(1MB), SP(64KB)

__device__ __forceinline__ float pd_score(float qx2, float qy2, float qz2, float4 c) {
    // fast screening score = 2*dot(q,c) - |c|^2 (query-constant -|q|^2 dropped; same ranking)
    return fmaf(qx2, c.x, fmaf(qy2, c.y, fmaf(qz2, c.z, -c.w)));
}

__device__ __forceinline__ unsigned sortable_f(float v) {
    unsigned b = __float_as_uint(v);
    return (b & 0x80000000u) ? ~b : (b | 0x80000000u);
}

// ---------------- kernel 1: weight folds + pts4 ----------------
__global__ __launch_bounds__(256) void kprep(
    const float* __restrict__ xyz,
    const float* __restrict__ w1, const float* __restrict__ b1,
    const float* __restrict__ g1, const float* __restrict__ bb1,
    const float* __restrict__ m1, const float* __restrict__ v1,
    const float* __restrict__ w2, const float* __restrict__ b2,
    const float* __restrict__ g2, const float* __restrict__ bb2,
    const float* __restrict__ m2, const float* __restrict__ v2,
    const float* __restrict__ wup, const float* __restrict__ bup,
    const float* __restrict__ gu, const float* __restrict__ bu2,
    const float* __restrict__ mu, const float* __restrict__ vu,
    float* __restrict__ wsf)
{
    const int tid = threadIdx.x;
    if (blockIdx.x == 0) {
        float* WKC = wsf + OFF_WKC/4;
        float* WAX = wsf + OFF_WAX/4;
        float* WBX = wsf + OFF_WBX/4;
        float* CBX = wsf + OFF_CBX/4;
        float* CBF = wsf + OFF_CBF/4;
        float* WUP = wsf + OFF_WUP/4;
        float* BUP = wsf + OFF_BUP/4;
        for (int i = tid; i < 16384; i += 256) {
            int c = i >> 7, o = i & 127, oo = o & 63;
            float s2 = g2[oo] * rsqrtf(v2[oo] + 1e-5f);
            float val = (o < 64) ? s2 * w2[oo*256 + c]
                                 : s2 * (w2[oo*256 + 128 + c] - w2[oo*256 + c]);
            WKC[c*128 + o] = val;
        }
        if (tid < 64) {
            int o = tid;
            float s1 = g1[o] * rsqrtf(v1[o] + 1e-5f);
            WAX[o*4+0] = s1 * w1[o*6+0];
            WAX[o*4+1] = s1 * w1[o*6+1];
            WAX[o*4+2] = s1 * w1[o*6+2];
            WAX[o*4+3] = 0.f;
            WBX[o*4+0] = s1 * (w1[o*6+3] - w1[o*6+0]);
            WBX[o*4+1] = s1 * (w1[o*6+4] - w1[o*6+1]);
            WBX[o*4+2] = s1 * (w1[o*6+5] - w1[o*6+2]);
            WBX[o*4+3] = 0.f;
            CBX[o] = s1 * b1[o] + (bb1[o] - m1[o]*s1);
            float s2b = g2[o] * rsqrtf(v2[o] + 1e-5f);
            CBF[o] = s2b * b2[o] + (bb2[o] - m2[o]*s2b);
        }
        if (tid < 128) {
            int o = tid;
            float su = gu[o] * rsqrtf(vu[o] + 1e-5f);
            for (int c = 0; c < 16; ++c) WUP[o*16+c] = su * wup[o*16+c];
            BUP[o] = su * bup[o] + (bu2[o] - mu[o]*su);
        }
    } else {
        // np-f32-exact |p|^2: ((x*x + y*y) + z*z), no FMA contraction, matching
        // np.sum(xyz*xyz, axis=1) sequential f32 reduction.
        #pragma clang fp contract(off)
        int n = (blockIdx.x - 1)*256 + tid;
        float x = xyz[n], y = xyz[NPT+n], z = xyz[2*NPT+n];
        float4 p; p.x = x; p.y = y; p.z = z;
        p.w = (x*x + y*y) + z*z;
        ((float4*)(wsf + OFF_PTS4/4))[n] = p;
    }
}

// ---------------- kernel 2: per-query threshold tau ----------------
// tau[q] = (20th-largest of union(8 per-thread top-6) over candidates [0,1024)) - margin.
// union-20th <= subset-20th <= full-20th, and the 5e-4 margin covers all screening-score
// vs np-f32-pd discrepancies (<= ~3e-5) -> bitmap survivors are a superset of np's top-20.
// Candidate region (16KB) is L1-resident -> read pts4 directly, no LDS staging.
__global__ __launch_bounds__(256) void ktau(const float* __restrict__ wsf, float* __restrict__ tau)
{
    const float4* pts4 = (const float4*)(wsf + OFF_PTS4/4);
    __shared__ float t6[32][8][6];
    const int tid = threadIdx.x;
    const int ql = tid >> 3, t = tid & 7;
    const int q = blockIdx.x*32 + ql;
    float4 qp = pts4[q];
    float qx2 = qp.x + qp.x, qy2 = qp.y + qp.y, qz2 = qp.z + qp.z;
    float v0 = NEG_INF, v1 = NEG_INF, v2 = NEG_INF, v3 = NEG_INF, v4 = NEG_INF, v5 = NEG_INF;
    const int jb = t*128;
    for (int i = 0; i < 128; ++i) {
        float v = pd_score(qx2, qy2, qz2, pts4[jb + i]);
        float n5 = v > v5 ? (v > v4 ? v4 : v) : v5;
        float n4 = v > v4 ? (v > v3 ? v3 : v) : v4;
        float n3 = v > v3 ? (v > v2 ? v2 : v) : v3;
        float n2 = v > v2 ? (v > v1 ? v1 : v) : v2;
        float n1 = v > v1 ? (v > v0 ? v0 : v) : v1;
        float n0 = v > v0 ? v : v0;
        v0 = n0; v1 = n1; v2 = n2; v3 = n3; v4 = n4; v5 = n5;
    }
    t6[ql][t][0] = v0; t6[ql][t][1] = v1; t6[ql][t][2] = v2;
    t6[ql][t][3] = v3; t6[ql][t][4] = v4; t6[ql][t][5] = v5;
    __syncthreads();
    if (t == 0) {
        int p0=0,p1=0,p2=0,p3=0,p4=0,p5=0,p6=0,p7=0;
        float last = NEG_INF;
        for (int it = 0; it < 20; ++it) {
            float best = NEG_INF; int bl = -1;
#define CHK(L, PL) { float h = t6[ql][L][(PL) < 6 ? (PL) : 5]; if (((PL) < 6) && (h > best)) { best = h; bl = L; } }
            CHK(0,p0) CHK(1,p1) CHK(2,p2) CHK(3,p3) CHK(4,p4) CHK(5,p5) CHK(6,p6) CHK(7,p7)
#undef CHK
            p0 += (bl==0); p1 += (bl==1); p2 += (bl==2); p3 += (bl==3);
            p4 += (bl==4); p5 += (bl==5); p6 += (bl==6); p7 += (bl==7);
            last = best;
        }
        tau[q] = last - 5e-4f;   // conservative margin (covers fmaf-chain vs np-f32 rounding)
    }
}

// ---------------- kernel 3: INVERTED scan — candidate-per-lane, ballot bitmap -------
// Rounds 11-14: query-per-thread + wave-uniform candidate scalar stream is structurally
// stuck at ~62us (s_load latency; all variations regressed: 91us, 165us). INVERT: lane
// holds ONE candidate (2c + -|c|^2 in VGPRs, loaded once); queries stream through the
// SCALAR pipe (20KB/wave, sequential, K$-hot). __ballot(acc>=tau) = the 64 candidate
// bits of query q in one instr (wave-uniform SGPR pair). Lane j keeps query j's words
// via branchless v_cndmask selects (writelane builtin doesn't exist on HIP/gfx950).
// Per query per wave: 3 v_fma + 1 ballot-cmp + v_cmp_eq + 2 cndmask ~ 8 VALU, VGPR ~40.
// Masks staged in LDS [1024][18] (72KB, 2 blocks/CU), dense 64B-sector copy-out
// (round-11-proven: WRITE_SIZE stays exactly 32MB).
// Score assoc: acc = fma(qz,2cz, fma(qy,2cy, fma(qx,2cx, -|c|2))) vs tau — within
// ~1e-5 of ktau's chain; the 5e-4 tau margin covers it (superset guarantee intact).
__global__ __launch_bounds__(512) void kpush(const float* __restrict__ wsf,
                                             const float* __restrict__ tau,
                                             unsigned* __restrict__ bm)
{
    const float4* pts4 = (const float4*)(wsf + OFF_PTS4/4);
    __shared__ unsigned lds[1024][18];   // 72KB; row=query, cols 0..15 = 16 words, pad 18
    const int tid = threadIdx.x;
    const int wave = tid >> 6, lane = tid & 63;
    const int cblk = blockIdx.x & 31;    // 32 candidate blocks x 512 cands
    const int qsp  = blockIdx.x >> 5;    // 16 query splits x 1024 queries
    const int cbase = cblk*512 + wave*64;
    const int qbase = qsp*1024;

    float4 c = pts4[cbase + lane];
    float cx2 = c.x + c.x, cy2 = c.y + c.y, cz2 = c.z + c.z;
    float negw = -c.w;

    for (int b = 0; b < 16; ++b) {
        unsigned vlo = 0u, vhi = 0u;
        const int q0 = qbase + b*64;
#pragma unroll 8
        for (int j = 0; j < 64; ++j) {
            const int q = q0 + j;
            float4 qp = pts4[q];          // wave-uniform -> scalar loads
            float tq  = tau[q];
            float acc = fmaf(qp.z, cz2, fmaf(qp.y, cy2, fmaf(qp.x, cx2, negw)));
            unsigned long long m = __ballot(acc >= tq);   // wave-uniform (sgpr pair)
            bool sel = (lane == j);
            vlo = sel ? (unsigned)m : vlo;          // v_cndmask, scalar src
            vhi = sel ? (unsigned)(m >> 32) : vhi;  // v_cndmask, scalar src
        }
        // lane i now holds the 2 bitmap words of query q0+i for this wave's 64 cands
        const int row = b*64 + lane;
        lds[row][wave*2]     = vlo;
        lds[row][wave*2 + 1] = vhi;
    }
    __syncthreads();
    // dense copy-out: each thread 2 query-rows, one fully-dirty 64B sector each
    for (int r = tid; r < 1024; r += 512) {
        const unsigned* src = &lds[r][0];
        uint4* dst = (uint4*)(bm + (size_t)(qbase + r)*512 + cblk*16);
        uint4 o0, o1, o2, o3;
        o0.x = src[0];  o0.y = src[1];  o0.z = src[2];  o0.w = src[3];
        o1.x = src[4];  o1.y = src[5];  o1.z = src[6];  o1.w = src[7];
        o2.x = src[8];  o2.y = src[9];  o2.z = src[10]; o2.w = src[11];
        o3.x = src[12]; o3.y = src[13]; o3.z = src[14]; o3.w = src[15];
        dst[0] = o0; dst[1] = o1; dst[2] = o2; dst[3] = o3;
    }
}

// ---------------- kernel 4: exact top-20 from bitmap — balanced pool-and-rank -------
//  (A) balanced extraction: popc + wave prefix-sum reserve, short-body bit-walk writes
//      survivor indices (u16) to an LDS pool;
//  (B) uniform round-robin scoring: ceil(nS/64) rounds, each lane scores one pooled
//      survivor (np-f32 bit-exact, fp contract off) into its register top-8.
// Then: bitonic sort of lane maxima -> theta = 20th-largest; compact keys >= theta to
// u64 pool; exact rank = #greater keys; rank<20 -> knn (exact np top_k order).
// Coverage: round-robin scatters top-20 over lanes; drop needs >8 in one lane
// (P ~ 6e-10 * 16384 ~ 1e-5 on this fixed data). Keys unique -> exact np order.
#define KS(A,B) V##A = (kk > V##B) ? V##B : ((kk > V##A) ? kk : V##A);
__global__ __launch_bounds__(256) void ksel(const float* __restrict__ wsf,
                                            const unsigned* __restrict__ bm,
                                            unsigned* __restrict__ knn)
{
    #pragma clang fp contract(off)
    const float4* pts4 = (const float4*)(wsf + OFF_PTS4/4);
    __shared__ unsigned short spool[4][1024];
    __shared__ unsigned long long pool[4][128];
    const int lane = threadIdx.x & 63;
    const int qw   = threadIdx.x >> 6;
    const int q = blockIdx.x*4 + qw;
    float4 qp = pts4[q];

    // ---- stage A: balanced survivor-index extraction ----
    const uint4* row = (const uint4*)(bm + (size_t)q*512) + lane*2;
    uint4 a0 = row[0], a1 = row[1];
    unsigned wv[8] = {a0.x, a0.y, a0.z, a0.w, a1.x, a1.y, a1.z, a1.w};
    int scnt = 0;
#pragma unroll
    for (int t = 0; t < 8; ++t) scnt += __popc(wv[t]);
    int spre = scnt;
#pragma unroll
    for (int o = 1; o < 64; o <<= 1) {
        int t2 = __shfl_up(spre, o, 64);
        spre += (lane >= o) ? t2 : 0;
    }
    int nS = __shfl(spre, 63, 64);
    if (nS > 1024) nS = 1024;   // ~35-sigma guard; never trips statistically
    unsigned short* sp = spool[qw];
    int wptr = spre - scnt;
#pragma unroll
    for (int t = 0; t < 8; ++t) {
        unsigned w = wv[t];
        const int wbase = (lane*8 + t)*32;
        while (w) {
            int b = __ffs(w) - 1; w &= w - 1;
            if (wptr < 1024) sp[wptr] = (unsigned short)(wbase + b);
            ++wptr;
        }
    }
    __syncthreads();

    // ---- stage B: uniform round-robin scoring into register top-8 ----
    unsigned long long V0=0,V1=0,V2=0,V3=0,V4=0,V5=0,V6=0,V7=0;
    const int rounds = (nS + 63) >> 6;
    for (int r = 0; r < rounds; ++r) {
        int i = r*64 + lane;
        bool val = i < nS;
        int j = val ? (int)sp[i] : 0;
        float4 cp = pts4[j];
        float d  = (qp.x*cp.x + qp.y*cp.y) + qp.z*cp.z;
        float pd = (2.0f*d - qp.w) - cp.w;
        unsigned long long kk = val ? (((unsigned long long)sortable_f(pd) << 14)
                                      | (unsigned long long)(16383 - j)) : 0ull;
        if (kk > V7) {
            KS(7,6) KS(6,5) KS(5,4) KS(4,3) KS(3,2) KS(2,1) KS(1,0)
            V0 = (kk > V0) ? kk : V0;
        }
    }

    // ---- bitonic ascending sort of lane maxima; theta at lane 44 (20th largest) ----
    unsigned long long ss = V0;
#pragma unroll
    for (int k = 2; k <= 64; k <<= 1) {
#pragma unroll
        for (int j = k >> 1; j > 0; j >>= 1) {
            unsigned long long o = __shfl_xor(ss, j, 64);
            bool up = ((lane & k) == 0);
            bool lower = ((lane & j) == 0);
            ss = (lower == up) ? ((ss < o) ? ss : o) : ((ss > o) ? ss : o);
        }
    }
    unsigned long long theta = __shfl(ss, 44, 64);

    // ---- compact kept keys >= theta into u64 LDS pool ----
    int kcnt = (int)(V0 >= theta) + (int)(V1 >= theta) + (int)(V2 >= theta)
             + (int)(V3 >= theta) + (int)(V4 >= theta) + (int)(V5 >= theta)
             + (int)(V6 >= theta) + (int)(V7 >= theta);
    int ksc = kcnt;
#pragma unroll
    for (int o = 1; o < 64; o <<= 1) {
        int t2 = __shfl_up(ksc, o, 64);
        ksc += (lane >= o) ? t2 : 0;
    }
    int C = __shfl(ksc, 63, 64);
    int kbase = ksc - kcnt;
    if (C > 128) C = 128;
    unsigned long long* pq = pool[qw];
#define WPOOL(I, VI) if (I < kcnt) { int p = kbase + I; if (p < 128) pq[p] = VI; }
    WPOOL(0, V0) WPOOL(1, V1) WPOOL(2, V2) WPOOL(3, V3)
    WPOOL(4, V4) WPOOL(5, V5) WPOOL(6, V6) WPOOL(7, V7)
#undef WPOOL
    __syncthreads();

    // ---- rank by counting greater pool keys (broadcast LDS reads) ----
    bool h1 = lane < C;
    bool h2 = (lane + 64) < C;
    unsigned long long k1 = h1 ? pq[lane] : 0ull;
    unsigned long long k2 = h2 ? pq[lane + 64] : 0ull;
    int r1 = 0, r2 = 0;
    for (int i = 0; i < C; ++i) {
        unsigned long long ki = pq[i];
        r1 += (int)(ki > k1);
        r2 += (int)(ki > k2);
    }
    unsigned* kout = knn + (size_t)q*20;
    if (h1 && r1 < 20) kout[r1] = 16383u - (unsigned)(k1 & 0x3FFFull);
    if (h2 && r2 < 20) kout[r2] = 16383u - (unsigned)(k2 & 0x3FFFull);
}

// ---------------- kernel 5: GEMM for feature part of G and T2 ----------------
// G[n][64+o] = F_n . WA_f[o]   ;  T2[n][64+o] = F_n . WB_f[o] + CB_f[o]
__global__ __launch_bounds__(128) void kgemm(const float* __restrict__ feat,
                                             const float* __restrict__ wsf,
                                             float* __restrict__ G, float* __restrict__ T2)
{
    __shared__ float As[32][64];
    __shared__ float Bs[32][128];
    const float* WKC = wsf + OFF_WKC/4;
    const float* CBF = wsf + OFF_CBF/4;
    const int tid = threadIdx.x;
    const int n0 = blockIdx.x * 64;
    const int tx = tid & 15, ty = tid >> 4;
    float acc[8][8] = {};
    for (int kc = 0; kc < 4; ++kc) {
        int c0 = kc * 32;
        for (int i = tid; i < 2048; i += 128) {
            int cl = i >> 6, nl = i & 63;
            As[cl][nl] = feat[(size_t)(c0 + cl)*NPT + n0 + nl];
        }
        for (int i = tid; i < 4096; i += 128) {
            int cl = i >> 7, ol = i & 127;
            Bs[cl][ol] = WKC[(c0 + cl)*128 + ol];
        }
        __syncthreads();
        for (int cc = 0; cc < 32; ++cc) {
            float av[8], bv[8];
#pragma unroll
            for (int r = 0; r < 8; ++r) av[r] = As[cc][ty*8 + r];
#pragma unroll
            for (int s = 0; s < 8; ++s) bv[s] = Bs[cc][tx*8 + s];
#pragma unroll
            for (int r = 0; r < 8; ++r)
#pragma unroll
                for (int s = 0; s < 8; ++s)
                    acc[r][s] = fmaf(av[r], bv[s], acc[r][s]);
        }
        __syncthreads();
    }
#pragma unroll
    for (int r = 0; r < 8; ++r) {
        int n = n0 + ty*8 + r;
        if (tx < 8) {
            float* dst = G + (size_t)n*128 + 64 + tx*8;
#pragma unroll
            for (int s = 0; s < 8; ++s) dst[s] = acc[r][s];
        } else {
            int ob = (tx - 8)*8;
            float* dst = T2 + (size_t)n*128 + 64 + ob;
#pragma unroll
            for (int s = 0; s < 8; ++s) dst[s] = acc[r][s] + CBF[ob + s];
        }
    }
}

// ---------------- kernel 6: xyz part of G and T2 ----------------
__global__ __launch_bounds__(256) void kxpart(const float* __restrict__ xyz,
                                              const float* __restrict__ wsf,
                                              float* __restrict__ G, float* __restrict__ T2)
{
    const float4* WAX = (const float4*)(wsf + OFF_WAX/4);
    const float4* WBX = (const float4*)(wsf + OFF_WBX/4);
    const float*  CBX = wsf + OFF_CBX/4;
    const int tid = threadIdx.x;
    const int o = tid & 63;
    const int n = blockIdx.x*4 + (tid >> 6);
    float x = xyz[n], y = xyz[NPT+n], z = xyz[2*NPT+n];
    float4 A = WAX[o], B = WBX[o];
    G[(size_t)n*128 + o]  = fmaf(x, A.x, fmaf(y, A.y, z*A.z));
    T2[(size_t)n*128 + o] = fmaf(x, B.x, fmaf(y, B.y, fmaf(z, B.z, CBX[o])));
}

// ---------------- kernel 7: gather + max-pool + f1/f2 + partials ----------------
__global__ __launch_bounds__(256) void kgather(const float* __restrict__ wsf,
                                               const unsigned* __restrict__ knn,
                                               const float* __restrict__ G,
                                               const float* __restrict__ T2,
                                               const float* __restrict__ wd1,
                                               const float* __restrict__ wd2,
                                               float* __restrict__ F, float* __restrict__ F1,
                                               float* __restrict__ F2, float* __restrict__ SPm,
                                               float* __restrict__ PART)
{
    __shared__ float fsh[64][136];
    __shared__ float w1s[16][136];
    __shared__ float w2s[16][136];
    __shared__ float f1sh[64][16];
    __shared__ float f2p[64][4];
    const int tid = threadIdx.x;
    for (int i = tid; i < 2048; i += 256) {
        int o = i >> 7, cc = i & 127;
        w1s[o][cc] = wd1[i];
        w2s[o][cc] = wd2[i];
    }
    const int nl = tid >> 2, qt = tid & 3;
    const int n = blockIdx.x*64 + nl;
    const unsigned* ip = knn + (size_t)n*20;
    float acc[32];
#pragma unroll
    for (int e = 0; e < 32; ++e) acc[e] = NEG_INF;
    for (int k = 0; k < 20; ++k) {
        unsigned j = ip[k];
        const float4* g4 = (const float4*)(G + (size_t)j*128 + qt*32);
#pragma unroll
        for (int r = 0; r < 8; ++r) {
            float4 gv = g4[r];
            acc[r*4+0] = fmaxf(acc[r*4+0], gv.x);
            acc[r*4+1] = fmaxf(acc[r*4+1], gv.y);
            acc[r*4+2] = fmaxf(acc[r*4+2], gv.z);
            acc[r*4+3] = fmaxf(acc[r*4+3], gv.w);
        }
    }
    const float4* t4 = (const float4*)(T2 + (size_t)n*128 + qt*32);
    float4* fg = (float4*)(F + (size_t)n*128 + qt*32);
    float4* fs = (float4*)&fsh[nl][qt*32];
#pragma unroll
    for (int r = 0; r < 8; ++r) {
        float4 tv = t4[r];
        float4 o4;
        o4.x = fmaxf(acc[r*4+0] + tv.x, 0.f);
        o4.y = fmaxf(acc[r*4+1] + tv.y, 0.f);
        o4.z = fmaxf(acc[r*4+2] + tv.z, 0.f);
        o4.w = fmaxf(acc[r*4+3] + tv.w, 0.f);
        fg[r] = o4; fs[r] = o4;
    }
    __syncthreads();
    // phase 2: f1/f2 (4 outputs each per thread)
    float a1[4] = {0,0,0,0}, a2[4] = {0,0,0,0};
    const int ob = qt*4;
    for (int c4 = 0; c4 < 32; ++c4) {
        float4 fv = ((const float4*)&fsh[nl][0])[c4];
#pragma unroll
        for (int r = 0; r < 4; ++r) {
            float4 wv1 = ((const float4*)&w1s[ob + r][0])[c4];
            float4 wv2 = ((const float4*)&w2s[ob + r][0])[c4];
            a1[r] = fmaf(fv.x, wv1.x, fmaf(fv.y, wv1.y, fmaf(fv.z, wv1.z, fmaf(fv.w, wv1.w, a1[r]))));
            a2[r] = fmaf(fv.x, wv2.x, fmaf(fv.y, wv2.y, fmaf(fv.z, wv2.z, fmaf(fv.w, wv2.w, a2[r]))));
        }
    }
    float s2sum = 0.f;
#pragma unroll
    for (int r = 0; r < 4; ++r) {
        a1[r] = fmaxf(a1[r], 0.f);
        a2[r] = fmaxf(a2[r], 0.f);
        s2sum += a2[r];
        F1[(size_t)n*16 + ob + r] = a1[r];
        F2[(size_t)n*16 + ob + r] = a2[r];
        f1sh[nl][ob + r] = a1[r];
    }
    f2p[nl][qt] = s2sum;
    __syncthreads();
    if (qt == 0)
        SPm[n] = (f2p[nl][0] + f2p[nl][1] + f2p[nl][2] + f2p[nl][3]) * (1.0f/16.0f);
    if (tid < 16) {
        float s = 0.f;
        for (int r = 0; r < 64; ++r) s += f1sh[r][tid];
        PART[blockIdx.x*16 + tid] = s;
    }
}

// ---------------- kernel 8: reduce channel mean ----------------
__global__ __launch_bounds__(64) void kch(const float* __restrict__ PART, float* __restrict__ CH)
{
    const int tid = threadIdx.x;
    if (tid < 16) {
        float s = 0.f;
        for (int b = 0; b < 256; ++b) s += PART[b*16 + tid];
        CH[tid] = s * (1.0f/16384.0f);
    }
}

// ---------------- kernel 9: final head + mish + transpose ----------------
__global__ __launch_bounds__(64) void kfinal(const float* __restrict__ wsf,
                                             const float* __restrict__ F,
                                             const float* __restrict__ F1,
                                             const float* __restrict__ F2,
                                             const float* __restrict__ SPm,
                                             const float* __restrict__ CH,
                                             float* __restrict__ out)
{
    const float* WUP = wsf + OFF_WUP/4;
    const float* BUP = wsf + OFF_BUP/4;
    const int n = blockIdx.x*64 + threadIdx.x;
    float spv = SPm[n];
    float fin[16];
    const float4* f14 = (const float4*)(F1 + (size_t)n*16);
    const float4* f24 = (const float4*)(F2 + (size_t)n*16);
#pragma unroll
    for (int c4 = 0; c4 < 4; ++c4) {
        float4 a = f14[c4], b = f24[c4];
        fin[c4*4+0] = sqrtf(fmaf(CH[c4*4+0], spv, 1e-12f)) + a.x + b.x;
        fin[c4*4+1] = sqrtf(fmaf(CH[c4*4+1], spv, 1e-12f)) + a.y + b.y;
        fin[c4*4+2] = sqrtf(fmaf(CH[c4*4+2], spv, 1e-12f)) + a.z + b.z;
        fin[c4*4+3] = sqrtf(fmaf(CH[c4*4+3], spv, 1e-12f)) + a.w + b.w;
    }
    const float4* fF = (const float4*)(F + (size_t)n*128);
    for (int o4 = 0; o4 < 32; ++o4) {
        float4 fv = fF[o4];
        float fa[4] = {fv.x, fv.y, fv.z, fv.w};
#pragma unroll
        for (int e = 0; e < 4; ++e) {
            int o = o4*4 + e;
            float u = BUP[o];
#pragma unroll
            for (int c = 0; c < 16; ++c) u = fmaf(fin[c], WUP[o*16 + c], u);
            u = fmaxf(u, 0.f);
            float fl = fa[e] - u;
            // mish: fl * tanh(softplus(fl)) ; tanh(log1p(e^x)) = ((1+e^x)^2-1)/((1+e^x)^2+1)
            float flc = fminf(fl, 15.f);
            float t = expf(flc);
            float w = 1.f + t;
            float w2 = w*w;
            float th = (w2 - 1.f) / (w2 + 1.f);
            float res = (fl > 15.f) ? fl : fl * th;
            out[(size_t)o*NPT + n] = res;
        }
    }
}

extern "C" void kernel_launch(void* const* d_in, const int* in_sizes, int n_in,
                              void* d_out, int out_size, void* d_ws, size_t ws_size,
                              hipStream_t stream) {
    const float* xyz  = (const float*)d_in[0];
    const float* feat = (const float*)d_in[1];
    const float* w1   = (const float*)d_in[2];
    const float* b1   = (const float*)d_in[3];
    const float* g1   = (const float*)d_in[4];
    const float* bb1  = (const float*)d_in[5];
    const float* m1   = (const float*)d_in[6];
    const float* v1   = (const float*)d_in[7];
    const float* w2   = (const float*)d_in[8];
    const float* b2   = (const float*)d_in[9];
    const float* g2   = (const float*)d_in[10];
    const float* bb2  = (const float*)d_in[11];
    const float* m2   = (const float*)d_in[12];
    const float* v2   = (const float*)d_in[13];
    const float* wd1  = (const float*)d_in[14];
    const float* wd2  = (const float*)d_in[15];
    const float* wup  = (const float*)d_in[16];
    const float* bup  = (const float*)d_in[17];
    const float* gu   = (const float*)d_in[18];
    const float* bu2  = (const float*)d_in[19];
    const float* mu   = (const float*)d_in[20];
    const float* vu   = (const float*)d_in[21];
    float* out = (float*)d_out;

    float* wsf = (float*)d_ws;
    unsigned* bm   = (unsigned*)((char*)d_ws + OFF_R);
    unsigned* knn  = (unsigned*)((char*)d_ws + OFF_KNN);
    float* TAU  = (float*)((char*)d_ws + OFF_TAU);
    float* PART = (float*)((char*)d_ws + OFF_PART);
    float* CH   = (float*)((char*)d_ws + OFF_CH);
    // region R reused after ksel
    float* G  = (float*)((char*)d_ws + OFF_R);
    float* T2 = G  + 2097152;
    float* F  = T2 + 2097152;
    float* F1 = F  + 2097152;
    float* F2 = F1 + 262144;
    float* SPm = F2 + 262144;

    kprep<<<dim3(65),  dim3(256), 0, stream>>>(xyz, w1,b1,g1,bb1,m1,v1,
                                               w2,b2,g2,bb2,m2,v2,
                                               wup,bup,gu,bu2,mu,vu, wsf);
    ktau <<<dim3(512), dim3(256), 0, stream>>>(wsf, TAU);
    kpush<<<dim3(512), dim3(512), 0, stream>>>(wsf, TAU, bm);
    ksel <<<dim3(4096), dim3(256), 0, stream>>>(wsf, bm, knn);
    kgemm<<<dim3(256), dim3(128), 0, stream>>>(feat, wsf, G, T2);
    kxpart<<<dim3(4096), dim3(256), 0, stream>>>(xyz, wsf, G, T2);
    kgather<<<dim3(256), dim3(256), 0, stream>>>(wsf, knn, G, T2, wd1, wd2, F, F1, F2, SPm, PART);
    kch  <<<dim3(1),   dim3(64), 0, stream>>>(PART, CH);
    kfinal<<<dim3(256), dim3(64), 0, stream>>>(wsf, F, F1, F2, SPm, CH, out);
}

// Round 17
// 254.218 us; speedup vs baseline: 1.3162x; 1.1620x over previous
//
#include <hip/hip_runtime.h>

#define NPT 16384
#define NEG_INF (-3.402823466e38f)

// ---- workspace byte offsets ----
#define OFF_PTS4  0u            // 16384 * 16          = 262144
#define OFF_WKC   262144u       // 128*128*4           = 65536
#define OFF_WAX   327680u       // 64*4*4              = 1024
#define OFF_WBX   328704u       // 1024
#define OFF_CBX   329728u       // 256
#define OFF_CBF   329984u       // 256
#define OFF_WUP   330240u       // 128*16*4            = 8192
#define OFF_BUP   338432u       // 512
#define OFF_TAU   338944u       // 16384*4             = 65536
#define OFF_KNN   666624u       // 16384*20*4          = 1310720
#define OFF_PART  1977344u      // 256*16*4            = 16384
#define OFF_CH    1993728u      // 256
#define OFF_R     1994240u      // reused: survivor bitmap u32[16384][512] = 33554432
                                // after ksel: G(8MB), T2(8MB), F(8MB), F1(1MB), F2(1MB), SP(64KB)

__device__ __forceinline__ float pd_score(float qx2, float qy2, float qz2, float4 c) {
    // fast screening score = 2*dot(q,c) - |c|^2 (query-constant -|q|^2 dropped; same ranking)
    return fmaf(qx2, c.x, fmaf(qy2, c.y, fmaf(qz2, c.z, -c.w)));
}

__device__ __forceinline__ unsigned sortable_f(float v) {
    unsigned b = __float_as_uint(v);
    return (b & 0x80000000u) ? ~b : (b | 0x80000000u);
}

// ---------------- kernel 1: weight folds + pts4 ----------------
__global__ __launch_bounds__(256) void kprep(
    const float* __restrict__ xyz,
    const float* __restrict__ w1, const float* __restrict__ b1,
    const float* __restrict__ g1, const float* __restrict__ bb1,
    const float* __restrict__ m1, const float* __restrict__ v1,
    const float* __restrict__ w2, const float* __restrict__ b2,
    const float* __restrict__ g2, const float* __restrict__ bb2,
    const float* __restrict__ m2, const float* __restrict__ v2,
    const float* __restrict__ wup, const float* __restrict__ bup,
    const float* __restrict__ gu, const float* __restrict__ bu2,
    const float* __restrict__ mu, const float* __restrict__ vu,
    float* __restrict__ wsf)
{
    const int tid = threadIdx.x;
    if (blockIdx.x == 0) {
        float* WKC = wsf + OFF_WKC/4;
        float* WAX = wsf + OFF_WAX/4;
        float* WBX = wsf + OFF_WBX/4;
        float* CBX = wsf + OFF_CBX/4;
        float* CBF = wsf + OFF_CBF/4;
        float* WUP = wsf + OFF_WUP/4;
        float* BUP = wsf + OFF_BUP/4;
        for (int i = tid; i < 16384; i += 256) {
            int c = i >> 7, o = i & 127, oo = o & 63;
            float s2 = g2[oo] * rsqrtf(v2[oo] + 1e-5f);
            float val = (o < 64) ? s2 * w2[oo*256 + c]
                                 : s2 * (w2[oo*256 + 128 + c] - w2[oo*256 + c]);
            WKC[c*128 + o] = val;
        }
        if (tid < 64) {
            int o = tid;
            float s1 = g1[o] * rsqrtf(v1[o] + 1e-5f);
            WAX[o*4+0] = s1 * w1[o*6+0];
            WAX[o*4+1] = s1 * w1[o*6+1];
            WAX[o*4+2] = s1 * w1[o*6+2];
            WAX[o*4+3] = 0.f;
            WBX[o*4+0] = s1 * (w1[o*6+3] - w1[o*6+0]);
            WBX[o*4+1] = s1 * (w1[o*6+4] - w1[o*6+1]);
            WBX[o*4+2] = s1 * (w1[o*6+5] - w1[o*6+2]);
            WBX[o*4+3] = 0.f;
            CBX[o] = s1 * b1[o] + (bb1[o] - m1[o]*s1);
            float s2b = g2[o] * rsqrtf(v2[o] + 1e-5f);
            CBF[o] = s2b * b2[o] + (bb2[o] - m2[o]*s2b);
        }
        if (tid < 128) {
            int o = tid;
            float su = gu[o] * rsqrtf(vu[o] + 1e-5f);
            for (int c = 0; c < 16; ++c) WUP[o*16+c] = su * wup[o*16+c];
            BUP[o] = su * bup[o] + (bu2[o] - mu[o]*su);
        }
    } else {
        // np-f32-exact |p|^2: ((x*x + y*y) + z*z), no FMA contraction, matching
        // np.sum(xyz*xyz, axis=1) sequential f32 reduction.
        #pragma clang fp contract(off)
        int n = (blockIdx.x - 1)*256 + tid;
        float x = xyz[n], y = xyz[NPT+n], z = xyz[2*NPT+n];
        float4 p; p.x = x; p.y = y; p.z = z;
        p.w = (x*x + y*y) + z*z;
        ((float4*)(wsf + OFF_PTS4/4))[n] = p;
    }
}

// ---------------- kernel 2: per-query threshold tau ----------------
// tau[q] = (20th-largest of union(8 per-thread top-6) over candidates [0,1024)) - margin.
// union-20th <= subset-20th <= full-20th, and the 5e-4 margin covers all screening-score
// vs np-f32-pd discrepancies (<= ~3e-5) -> bitmap survivors are a superset of np's top-20.
// Candidate region (16KB) is L1-resident -> read pts4 directly, no LDS staging.
__global__ __launch_bounds__(256) void ktau(const float* __restrict__ wsf, float* __restrict__ tau)
{
    const float4* pts4 = (const float4*)(wsf + OFF_PTS4/4);
    __shared__ float t6[32][8][6];
    const int tid = threadIdx.x;
    const int ql = tid >> 3, t = tid & 7;
    const int q = blockIdx.x*32 + ql;
    float4 qp = pts4[q];
    float qx2 = qp.x + qp.x, qy2 = qp.y + qp.y, qz2 = qp.z + qp.z;
    float v0 = NEG_INF, v1 = NEG_INF, v2 = NEG_INF, v3 = NEG_INF, v4 = NEG_INF, v5 = NEG_INF;
    const int jb = t*128;
    for (int i = 0; i < 128; ++i) {
        float v = pd_score(qx2, qy2, qz2, pts4[jb + i]);
        float n5 = v > v5 ? (v > v4 ? v4 : v) : v5;
        float n4 = v > v4 ? (v > v3 ? v3 : v) : v4;
        float n3 = v > v3 ? (v > v2 ? v2 : v) : v3;
        float n2 = v > v2 ? (v > v1 ? v1 : v) : v2;
        float n1 = v > v1 ? (v > v0 ? v0 : v) : v1;
        float n0 = v > v0 ? v : v0;
        v0 = n0; v1 = n1; v2 = n2; v3 = n3; v4 = n4; v5 = n5;
    }
    t6[ql][t][0] = v0; t6[ql][t][1] = v1; t6[ql][t][2] = v2;
    t6[ql][t][3] = v3; t6[ql][t][4] = v4; t6[ql][t][5] = v5;
    __syncthreads();
    if (t == 0) {
        int p0=0,p1=0,p2=0,p3=0,p4=0,p5=0,p6=0,p7=0;
        float last = NEG_INF;
        for (int it = 0; it < 20; ++it) {
            float best = NEG_INF; int bl = -1;
#define CHK(L, PL) { float h = t6[ql][L][(PL) < 6 ? (PL) : 5]; if (((PL) < 6) && (h > best)) { best = h; bl = L; } }
            CHK(0,p0) CHK(1,p1) CHK(2,p2) CHK(3,p3) CHK(4,p4) CHK(5,p5) CHK(6,p6) CHK(7,p7)
#undef CHK
            p0 += (bl==0); p1 += (bl==1); p2 += (bl==2); p3 += (bl==3);
            p4 += (bl==4); p5 += (bl==5); p6 += (bl==6); p7 += (bl==7);
            last = best;
        }
        tau[q] = last - 5e-4f;   // conservative margin (covers fmaf-chain vs np-f32 rounding)
    }
}

// ---------------- kernel 3: streaming scan -> survivor BITMAP (round-12 proven) -----
// REVERT: rounds 13-16 tried 4 alternatives (2-cand-streams 91us, 2-queries 165us,
// ballot-inverted 97us) — all regressed vs this round-12 config's measured 61.7us.
// Structure: 1 query/thread, wave-uniform candidate scalar stream, 512-cand chunks
// (grid 2048 = 8 blocks/CU), staging 4 uint4/thread in LDS [256][5] (20KB), writeout
// = one fully-dirty 64B sector back-to-back (proven dense: WRITE_SIZE exactly 32MB).
// -tau folded into first fma (6 VALU/cand); compare s' >= |c|^2 (scalar src0).
// 5e-4 tau margin >> association delta -> superset guarantee intact.
__global__ __launch_bounds__(256) void kpush(const float* __restrict__ wsf,
                                             const float* __restrict__ tau,
                                             unsigned* __restrict__ bm)
{
    const float4* pts4 = (const float4*)(wsf + OFF_PTS4/4);
    __shared__ uint4 st[256][5];   // 20KB; slot [tid][g], pad 5 -> stride 20 words
    const int qg = blockIdx.x >> 5, c = blockIdx.x & 31;
    const int tid = threadIdx.x;
    const int jbase = c * 512;
    const int q = qg*256 + tid;
    float4 a = pts4[q];
    float ax2 = a.x + a.x, ay2 = a.y + a.y, az2 = a.z + a.z;
    float nt0 = -tau[q];
    for (int g = 0; g < 4; ++g) {
        unsigned wd[4];
#pragma unroll
        for (int u = 0; u < 4; ++u) {
            const int base = jbase + (g*4 + u)*32;
            unsigned w = 0u;
#pragma unroll
            for (int k = 0; k < 32; k += 4) {
                float4 d0 = pts4[base + k];
                float4 d1 = pts4[base + k + 1];
                float4 d2 = pts4[base + k + 2];
                float4 d3 = pts4[base + k + 3];
                float s0 = fmaf(az2, d0.z, fmaf(ay2, d0.y, fmaf(ax2, d0.x, nt0)));
                float s1 = fmaf(az2, d1.z, fmaf(ay2, d1.y, fmaf(ax2, d1.x, nt0)));
                float s2 = fmaf(az2, d2.z, fmaf(ay2, d2.y, fmaf(ax2, d2.x, nt0)));
                float s3 = fmaf(az2, d3.z, fmaf(ay2, d3.y, fmaf(ax2, d3.x, nt0)));
                w |= (s0 >= d0.w) ? (1u << k)       : 0u;
                w |= (s1 >= d1.w) ? (1u << (k + 1)) : 0u;
                w |= (s2 >= d2.w) ? (1u << (k + 2)) : 0u;
                w |= (s3 >= d3.w) ? (1u << (k + 3)) : 0u;
            }
            wd[u] = w;
        }
        uint4 o; o.x = wd[0]; o.y = wd[1]; o.z = wd[2]; o.w = wd[3];
        st[tid][g] = o;
    }
    // back-to-back 64B-sector writeout (thread-private slot: no barrier needed)
    uint4* dst = (uint4*)(bm + (size_t)q*512 + c*16);
#pragma unroll
    for (int g = 0; g < 4; ++g) dst[g] = st[tid][g];
}

// ---------------- kernel 4: exact top-20 from bitmap — balanced pool-and-rank -------
//  (A) balanced extraction: popc + wave prefix-sum reserve, short-body bit-walk writes
//      survivor indices (u16) to an LDS pool;
//  (B) uniform round-robin scoring: ceil(nS/64) rounds, each lane scores one pooled
//      survivor (np-f32 bit-exact, fp contract off) into its register top-8.
// Then: bitonic sort of lane maxima -> theta = 20th-largest; compact keys >= theta to
// u64 pool; exact rank = #greater keys; rank<20 -> knn (exact np top_k order).
// Coverage: round-robin scatters top-20 over lanes; drop needs >8 in one lane
// (P ~ 6e-10 * 16384 ~ 1e-5 on this fixed data). Keys unique -> exact np order.
#define KS(A,B) V##A = (kk > V##B) ? V##B : ((kk > V##A) ? kk : V##A);
__global__ __launch_bounds__(256) void ksel(const float* __restrict__ wsf,
                                            const unsigned* __restrict__ bm,
                                            unsigned* __restrict__ knn)
{
    #pragma clang fp contract(off)
    const float4* pts4 = (const float4*)(wsf + OFF_PTS4/4);
    __shared__ unsigned short spool[4][1024];
    __shared__ unsigned long long pool[4][128];
    const int lane = threadIdx.x & 63;
    const int qw   = threadIdx.x >> 6;
    const int q = blockIdx.x*4 + qw;
    float4 qp = pts4[q];

    // ---- stage A: balanced survivor-index extraction ----
    const uint4* row = (const uint4*)(bm + (size_t)q*512) + lane*2;
    uint4 a0 = row[0], a1 = row[1];
    unsigned wv[8] = {a0.x, a0.y, a0.z, a0.w, a1.x, a1.y, a1.z, a1.w};
    int scnt = 0;
#pragma unroll
    for (int t = 0; t < 8; ++t) scnt += __popc(wv[t]);
    int spre = scnt;
#pragma unroll
    for (int o = 1; o < 64; o <<= 1) {
        int t2 = __shfl_up(spre, o, 64);
        spre += (lane >= o) ? t2 : 0;
    }
    int nS = __shfl(spre, 63, 64);
    if (nS > 1024) nS = 1024;   // ~35-sigma guard; never trips statistically
    unsigned short* sp = spool[qw];
    int wptr = spre - scnt;
#pragma unroll
    for (int t = 0; t < 8; ++t) {
        unsigned w = wv[t];
        const int wbase = (lane*8 + t)*32;
        while (w) {
            int b = __ffs(w) - 1; w &= w - 1;
            if (wptr < 1024) sp[wptr] = (unsigned short)(wbase + b);
            ++wptr;
        }
    }
    __syncthreads();

    // ---- stage B: uniform round-robin scoring into register top-8 ----
    unsigned long long V0=0,V1=0,V2=0,V3=0,V4=0,V5=0,V6=0,V7=0;
    const int rounds = (nS + 63) >> 6;
    for (int r = 0; r < rounds; ++r) {
        int i = r*64 + lane;
        bool val = i < nS;
        int j = val ? (int)sp[i] : 0;
        float4 cp = pts4[j];
        float d  = (qp.x*cp.x + qp.y*cp.y) + qp.z*cp.z;
        float pd = (2.0f*d - qp.w) - cp.w;
        unsigned long long kk = val ? (((unsigned long long)sortable_f(pd) << 14)
                                      | (unsigned long long)(16383 - j)) : 0ull;
        if (kk > V7) {
            KS(7,6) KS(6,5) KS(5,4) KS(4,3) KS(3,2) KS(2,1) KS(1,0)
            V0 = (kk > V0) ? kk : V0;
        }
    }

    // ---- bitonic ascending sort of lane maxima; theta at lane 44 (20th largest) ----
    unsigned long long ss = V0;
#pragma unroll
    for (int k = 2; k <= 64; k <<= 1) {
#pragma unroll
        for (int j = k >> 1; j > 0; j >>= 1) {
            unsigned long long o = __shfl_xor(ss, j, 64);
            bool up = ((lane & k) == 0);
            bool lower = ((lane & j) == 0);
            ss = (lower == up) ? ((ss < o) ? ss : o) : ((ss > o) ? ss : o);
        }
    }
    unsigned long long theta = __shfl(ss, 44, 64);

    // ---- compact kept keys >= theta into u64 LDS pool ----
    int kcnt = (int)(V0 >= theta) + (int)(V1 >= theta) + (int)(V2 >= theta)
             + (int)(V3 >= theta) + (int)(V4 >= theta) + (int)(V5 >= theta)
             + (int)(V6 >= theta) + (int)(V7 >= theta);
    int ksc = kcnt;
#pragma unroll
    for (int o = 1; o < 64; o <<= 1) {
        int t2 = __shfl_up(ksc, o, 64);
        ksc += (lane >= o) ? t2 : 0;
    }
    int C = __shfl(ksc, 63, 64);
    int kbase = ksc - kcnt;
    if (C > 128) C = 128;
    unsigned long long* pq = pool[qw];
#define WPOOL(I, VI) if (I < kcnt) { int p = kbase + I; if (p < 128) pq[p] = VI; }
    WPOOL(0, V0) WPOOL(1, V1) WPOOL(2, V2) WPOOL(3, V3)
    WPOOL(4, V4) WPOOL(5, V5) WPOOL(6, V6) WPOOL(7, V7)
#undef WPOOL
    __syncthreads();

    // ---- rank by counting greater pool keys (broadcast LDS reads) ----
    bool h1 = lane < C;
    bool h2 = (lane + 64) < C;
    unsigned long long k1 = h1 ? pq[lane] : 0ull;
    unsigned long long k2 = h2 ? pq[lane + 64] : 0ull;
    int r1 = 0, r2 = 0;
    for (int i = 0; i < C; ++i) {
        unsigned long long ki = pq[i];
        r1 += (int)(ki > k1);
        r2 += (int)(ki > k2);
    }
    unsigned* kout = knn + (size_t)q*20;
    if (h1 && r1 < 20) kout[r1] = 16383u - (unsigned)(k1 & 0x3FFFull);
    if (h2 && r2 < 20) kout[r2] = 16383u - (unsigned)(k2 & 0x3FFFull);
}

// ---------------- kernel 5: GEMM for feature part of G and T2 ----------------
// G[n][64+o] = F_n . WA_f[o]   ;  T2[n][64+o] = F_n . WB_f[o] + CB_f[o]
__global__ __launch_bounds__(128) void kgemm(const float* __restrict__ feat,
                                             const float* __restrict__ wsf,
                                             float* __restrict__ G, float* __restrict__ T2)
{
    __shared__ float As[32][64];
    __shared__ float Bs[32][128];
    const float* WKC = wsf + OFF_WKC/4;
    const float* CBF = wsf + OFF_CBF/4;
    const int tid = threadIdx.x;
    const int n0 = blockIdx.x * 64;
    const int tx = tid & 15, ty = tid >> 4;
    float acc[8][8] = {};
    for (int kc = 0; kc < 4; ++kc) {
        int c0 = kc * 32;
        for (int i = tid; i < 2048; i += 128) {
            int cl = i >> 6, nl = i & 63;
            As[cl][nl] = feat[(size_t)(c0 + cl)*NPT + n0 + nl];
        }
        for (int i = tid; i < 4096; i += 128) {
            int cl = i >> 7, ol = i & 127;
            Bs[cl][ol] = WKC[(c0 + cl)*128 + ol];
        }
        __syncthreads();
        for (int cc = 0; cc < 32; ++cc) {
            float av[8], bv[8];
#pragma unroll
            for (int r = 0; r < 8; ++r) av[r] = As[cc][ty*8 + r];
#pragma unroll
            for (int s = 0; s < 8; ++s) bv[s] = Bs[cc][tx*8 + s];
#pragma unroll
            for (int r = 0; r < 8; ++r)
#pragma unroll
                for (int s = 0; s < 8; ++s)
                    acc[r][s] = fmaf(av[r], bv[s], acc[r][s]);
        }
        __syncthreads();
    }
#pragma unroll
    for (int r = 0; r < 8; ++r) {
        int n = n0 + ty*8 + r;
        if (tx < 8) {
            float* dst = G + (size_t)n*128 + 64 + tx*8;
#pragma unroll
            for (int s = 0; s < 8; ++s) dst[s] = acc[r][s];
        } else {
            int ob = (tx - 8)*8;
            float* dst = T2 + (size_t)n*128 + 64 + ob;
#pragma unroll
            for (int s = 0; s < 8; ++s) dst[s] = acc[r][s] + CBF[ob + s];
        }
    }
}

// ---------------- kernel 6: xyz part of G and T2 ----------------
__global__ __launch_bounds__(256) void kxpart(const float* __restrict__ xyz,
                                              const float* __restrict__ wsf,
                                              float* __restrict__ G, float* __restrict__ T2)
{
    const float4* WAX = (const float4*)(wsf + OFF_WAX/4);
    const float4* WBX = (const float4*)(wsf + OFF_WBX/4);
    const float*  CBX = wsf + OFF_CBX/4;
    const int tid = threadIdx.x;
    const int o = tid & 63;
    const int n = blockIdx.x*4 + (tid >> 6);
    float x = xyz[n], y = xyz[NPT+n], z = xyz[2*NPT+n];
    float4 A = WAX[o], B = WBX[o];
    G[(size_t)n*128 + o]  = fmaf(x, A.x, fmaf(y, A.y, z*A.z));
    T2[(size_t)n*128 + o] = fmaf(x, B.x, fmaf(y, B.y, fmaf(z, B.z, CBX[o])));
}

// ---------------- kernel 7: gather + max-pool + f1/f2 + partials ----------------
__global__ __launch_bounds__(256) void kgather(const float* __restrict__ wsf,
                                               const unsigned* __restrict__ knn,
                                               const float* __restrict__ G,
                                               const float* __restrict__ T2,
                                               const float* __restrict__ wd1,
                                               const float* __restrict__ wd2,
                                               float* __restrict__ F, float* __restrict__ F1,
                                               float* __restrict__ F2, float* __restrict__ SPm,
                                               float* __restrict__ PART)
{
    __shared__ float fsh[64][136];
    __shared__ float w1s[16][136];
    __shared__ float w2s[16][136];
    __shared__ float f1sh[64][16];
    __shared__ float f2p[64][4];
    const int tid = threadIdx.x;
    for (int i = tid; i < 2048; i += 256) {
        int o = i >> 7, cc = i & 127;
        w1s[o][cc] = wd1[i];
        w2s[o][cc] = wd2[i];
    }
    const int nl = tid >> 2, qt = tid & 3;
    const int n = blockIdx.x*64 + nl;
    const unsigned* ip = knn + (size_t)n*20;
    float acc[32];
#pragma unroll
    for (int e = 0; e < 32; ++e) acc[e] = NEG_INF;
    for (int k = 0; k < 20; ++k) {
        unsigned j = ip[k];
        const float4* g4 = (const float4*)(G + (size_t)j*128 + qt*32);
#pragma unroll
        for (int r = 0; r < 8; ++r) {
            float4 gv = g4[r];
            acc[r*4+0] = fmaxf(acc[r*4+0], gv.x);
            acc[r*4+1] = fmaxf(acc[r*4+1], gv.y);
            acc[r*4+2] = fmaxf(acc[r*4+2], gv.z);
            acc[r*4+3] = fmaxf(acc[r*4+3], gv.w);
        }
    }
    const float4* t4 = (const float4*)(T2 + (size_t)n*128 + qt*32);
    float4* fg = (float4*)(F + (size_t)n*128 + qt*32);
    float4* fs = (float4*)&fsh[nl][qt*32];
#pragma unroll
    for (int r = 0; r < 8; ++r) {
        float4 tv = t4[r];
        float4 o4;
        o4.x = fmaxf(acc[r*4+0] + tv.x, 0.f);
        o4.y = fmaxf(acc[r*4+1] + tv.y, 0.f);
        o4.z = fmaxf(acc[r*4+2] + tv.z, 0.f);
        o4.w = fmaxf(acc[r*4+3] + tv.w, 0.f);
        fg[r] = o4; fs[r] = o4;
    }
    __syncthreads();
    // phase 2: f1/f2 (4 outputs each per thread)
    float a1[4] = {0,0,0,0}, a2[4] = {0,0,0,0};
    const int ob = qt*4;
    for (int c4 = 0; c4 < 32; ++c4) {
        float4 fv = ((const float4*)&fsh[nl][0])[c4];
#pragma unroll
        for (int r = 0; r < 4; ++r) {
            float4 wv1 = ((const float4*)&w1s[ob + r][0])[c4];
            float4 wv2 = ((const float4*)&w2s[ob + r][0])[c4];
            a1[r] = fmaf(fv.x, wv1.x, fmaf(fv.y, wv1.y, fmaf(fv.z, wv1.z, fmaf(fv.w, wv1.w, a1[r]))));
            a2[r] = fmaf(fv.x, wv2.x, fmaf(fv.y, wv2.y, fmaf(fv.z, wv2.z, fmaf(fv.w, wv2.w, a2[r]))));
        }
    }
    float s2sum = 0.f;
#pragma unroll
    for (int r = 0; r < 4; ++r) {
        a1[r] = fmaxf(a1[r], 0.f);
        a2[r] = fmaxf(a2[r], 0.f);
        s2sum += a2[r];
        F1[(size_t)n*16 + ob + r] = a1[r];
        F2[(size_t)n*16 + ob + r] = a2[r];
        f1sh[nl][ob + r] = a1[r];
    }
    f2p[nl][qt] = s2sum;
    __syncthreads();
    if (qt == 0)
        SPm[n] = (f2p[nl][0] + f2p[nl][1] + f2p[nl][2] + f2p[nl][3]) * (1.0f/16.0f);
    if (tid < 16) {
        float s = 0.f;
        for (int r = 0; r < 64; ++r) s += f1sh[r][tid];
        PART[blockIdx.x*16 + tid] = s;
    }
}

// ---------------- kernel 8: reduce channel mean ----------------
__global__ __launch_bounds__(64) void kch(const float* __restrict__ PART, float* __restrict__ CH)
{
    const int tid = threadIdx.x;
    if (tid < 16) {
        float s = 0.f;
        for (int b = 0; b < 256; ++b) s += PART[b*16 + tid];
        CH[tid] = s * (1.0f/16384.0f);
    }
}

// ---------------- kernel 9: final head + mish + transpose ----------------
__global__ __launch_bounds__(64) void kfinal(const float* __restrict__ wsf,
                                             const float* __restrict__ F,
                                             const float* __restrict__ F1,
                                             const float* __restrict__ F2,
                                             const float* __restrict__ SPm,
                                             const float* __restrict__ CH,
                                             float* __restrict__ out)
{
    const float* WUP = wsf + OFF_WUP/4;
    const float* BUP = wsf + OFF_BUP/4;
    const int n = blockIdx.x*64 + threadIdx.x;
    float spv = SPm[n];
    float fin[16];
    const float4* f14 = (const float4*)(F1 + (size_t)n*16);
    const float4* f24 = (const float4*)(F2 + (size_t)n*16);
#pragma unroll
    for (int c4 = 0; c4 < 4; ++c4) {
        float4 a = f14[c4], b = f24[c4];
        fin[c4*4+0] = sqrtf(fmaf(CH[c4*4+0], spv, 1e-12f)) + a.x + b.x;
        fin[c4*4+1] = sqrtf(fmaf(CH[c4*4+1], spv, 1e-12f)) + a.y + b.y;
        fin[c4*4+2] = sqrtf(fmaf(CH[c4*4+2], spv, 1e-12f)) + a.z + b.z;
        fin[c4*4+3] = sqrtf(fmaf(CH[c4*4+3], spv, 1e-12f)) + a.w + b.w;
    }
    const float4* fF = (const float4*)(F + (size_t)n*128);
    for (int o4 = 0; o4 < 32; ++o4) {
        float4 fv = fF[o4];
        float fa[4] = {fv.x, fv.y, fv.z, fv.w};
#pragma unroll
        for (int e = 0; e < 4; ++e) {
            int o = o4*4 + e;
            float u = BUP[o];
#pragma unroll
            for (int c = 0; c < 16; ++c) u = fmaf(fin[c], WUP[o*16 + c], u);
            u = fmaxf(u, 0.f);
            float fl = fa[e] - u;
            // mish: fl * tanh(softplus(fl)) ; tanh(log1p(e^x)) = ((1+e^x)^2-1)/((1+e^x)^2+1)
            float flc = fminf(fl, 15.f);
            float t = expf(flc);
            float w = 1.f + t;
            float w2 = w*w;
            float th = (w2 - 1.f) / (w2 + 1.f);
            float res = (fl > 15.f) ? fl : fl * th;
            out[(size_t)o*NPT + n] = res;
        }
    }
}

extern "C" void kernel_launch(void* const* d_in, const int* in_sizes, int n_in,
                              void* d_out, int out_size, void* d_ws, size_t ws_size,
                              hipStream_t stream) {
    const float* xyz  = (const float*)d_in[0];
    const float* feat = (const float*)d_in[1];
    const float* w1   = (const float*)d_in[2];
    const float* b1   = (const float*)d_in[3];
    const float* g1   = (const float*)d_in[4];
    const float* bb1  = (const float*)d_in[5];
    const float* m1   = (const float*)d_in[6];
    const float* v1   = (const float*)d_in[7];
    const float* w2   = (const float*)d_in[8];
    const float* b2   = (const float*)d_in[9];
    const float* g2   = (const float*)d_in[10];
    const float* bb2  = (const float*)d_in[11];
    const float* m2   = (const float*)d_in[12];
    const float* v2   = (const float*)d_in[13];
    const float* wd1  = (const float*)d_in[14];
    const float* wd2  = (const float*)d_in[15];
    const float* wup  = (const float*)d_in[16];
    const float* bup  = (const float*)d_in[17];
    const float* gu   = (const float*)d_in[18];
    const float* bu2  = (const float*)d_in[19];
    const float* mu   = (const float*)d_in[20];
    const float* vu   = (const float*)d_in[21];
    float* out = (float*)d_out;

    float* wsf = (float*)d_ws;
    unsigned* bm   = (unsigned*)((char*)d_ws + OFF_R);
    unsigned* knn  = (unsigned*)((char*)d_ws + OFF_KNN);
    float* TAU  = (float*)((char*)d_ws + OFF_TAU);
    float* PART = (float*)((char*)d_ws + OFF_PART);
    float* CH   = (float*)((char*)d_ws + OFF_CH);
    // region R reused after ksel
    float* G  = (float*)((char*)d_ws + OFF_R);
    float* T2 = G  + 2097152;
    float* F  = T2 + 2097152;
    float* F1 = F  + 2097152;
    float* F2 = F1 + 262144;
    float* SPm = F2 + 262144;

    kprep<<<dim3(65),  dim3(256), 0, stream>>>(xyz, w1,b1,g1,bb1,m1,v1,
                                               w2,b2,g2,bb2,m2,v2,
                                               wup,bup,gu,bu2,mu,vu, wsf);
    ktau <<<dim3(512), dim3(256), 0, stream>>>(wsf, TAU);
    kpush<<<dim3(2048), dim3(256), 0, stream>>>(wsf, TAU, bm);
    ksel <<<dim3(4096), dim3(256), 0, stream>>>(wsf, bm, knn);
    kgemm<<<dim3(256), dim3(128), 0, stream>>>(feat, wsf, G, T2);
    kxpart<<<dim3(4096), dim3(256), 0, stream>>>(xyz, wsf, G, T2);
    kgather<<<dim3(256), dim3(256), 0, stream>>>(wsf, knn, G, T2, wd1, wd2, F, F1, F2, SPm, PART);
    kch  <<<dim3(1),   dim3(64), 0, stream>>>(PART, CH);
    kfinal<<<dim3(256), dim3(64), 0, stream>>>(wsf, F, F1, F2, SPm, CH, out);
}

// Round 18
// 219.828 us; speedup vs baseline: 1.5221x; 1.1564x over previous
//
#include <hip/hip_runtime.h>

#define NPT 16384
#define NEG_INF (-3.402823466e38f)

// ---- workspace byte offsets ----
#define OFF_PTS4  0u            // 16384 * 16          = 262144
#define OFF_WKC   262144u       // 128*128*4           = 65536
#define OFF_WAX   327680u       // 64*4*4              = 1024
#define OFF_WBX   328704u       // 1024
#define OFF_CBX   329728u       // 256
#define OFF_CBF   329984u       // 256
#define OFF_WUP   330240u       // 128*16*4            = 8192
#define OFF_BUP   338432u       // 512
#define OFF_TAU   338944u       // 16384*4 = 65536; DEAD after kpush -> reused as PART(512*16*4=32KB)
#define OFF_KNN   666624u       // 16384*20*4          = 1310720
#define OFF_CH    1993728u      // 256
#define OFF_R     1994240u      // reused: survivor bitmap u32[16384][512] = 33554432
                                // after ksel: G(8MB), T2(8MB), F(8MB), F1(1MB), F2(1MB), SP(64KB)

__device__ __forceinline__ float pd_score(float qx2, float qy2, float qz2, float4 c) {
    // fast screening score = 2*dot(q,c) - |c|^2 (query-constant -|q|^2 dropped; same ranking)
    return fmaf(qx2, c.x, fmaf(qy2, c.y, fmaf(qz2, c.z, -c.w)));
}

__device__ __forceinline__ unsigned sortable_f(float v) {
    unsigned b = __float_as_uint(v);
    return (b & 0x80000000u) ? ~b : (b | 0x80000000u);
}

// ---------------- kernel 1: weight folds + pts4 ----------------
__global__ __launch_bounds__(256) void kprep(
    const float* __restrict__ xyz,
    const float* __restrict__ w1, const float* __restrict__ b1,
    const float* __restrict__ g1, const float* __restrict__ bb1,
    const float* __restrict__ m1, const float* __restrict__ v1,
    const float* __restrict__ w2, const float* __restrict__ b2,
    const float* __restrict__ g2, const float* __restrict__ bb2,
    const float* __restrict__ m2, const float* __restrict__ v2,
    const float* __restrict__ wup, const float* __restrict__ bup,
    const float* __restrict__ gu, const float* __restrict__ bu2,
    const float* __restrict__ mu, const float* __restrict__ vu,
    float* __restrict__ wsf)
{
    const int tid = threadIdx.x;
    if (blockIdx.x == 0) {
        float* WKC = wsf + OFF_WKC/4;
        float* WAX = wsf + OFF_WAX/4;
        float* WBX = wsf + OFF_WBX/4;
        float* CBX = wsf + OFF_CBX/4;
        float* CBF = wsf + OFF_CBF/4;
        float* WUP = wsf + OFF_WUP/4;
        float* BUP = wsf + OFF_BUP/4;
        for (int i = tid; i < 16384; i += 256) {
            int c = i >> 7, o = i & 127, oo = o & 63;
            float s2 = g2[oo] * rsqrtf(v2[oo] + 1e-5f);
            float val = (o < 64) ? s2 * w2[oo*256 + c]
                                 : s2 * (w2[oo*256 + 128 + c] - w2[oo*256 + c]);
            WKC[c*128 + o] = val;
        }
        if (tid < 64) {
            int o = tid;
            float s1 = g1[o] * rsqrtf(v1[o] + 1e-5f);
            WAX[o*4+0] = s1 * w1[o*6+0];
            WAX[o*4+1] = s1 * w1[o*6+1];
            WAX[o*4+2] = s1 * w1[o*6+2];
            WAX[o*4+3] = 0.f;
            WBX[o*4+0] = s1 * (w1[o*6+3] - w1[o*6+0]);
            WBX[o*4+1] = s1 * (w1[o*6+4] - w1[o*6+1]);
            WBX[o*4+2] = s1 * (w1[o*6+5] - w1[o*6+2]);
            WBX[o*4+3] = 0.f;
            CBX[o] = s1 * b1[o] + (bb1[o] - m1[o]*s1);
            float s2b = g2[o] * rsqrtf(v2[o] + 1e-5f);
            CBF[o] = s2b * b2[o] + (bb2[o] - m2[o]*s2b);
        }
        if (tid < 128) {
            int o = tid;
            float su = gu[o] * rsqrtf(vu[o] + 1e-5f);
            for (int c = 0; c < 16; ++c) WUP[o*16+c] = su * wup[o*16+c];
            BUP[o] = su * bup[o] + (bu2[o] - mu[o]*su);
        }
    } else {
        // np-f32-exact |p|^2: ((x*x + y*y) + z*z), no FMA contraction, matching
        // np.sum(xyz*xyz, axis=1) sequential f32 reduction.
        #pragma clang fp contract(off)
        int n = (blockIdx.x - 1)*256 + tid;
        float x = xyz[n], y = xyz[NPT+n], z = xyz[2*NPT+n];
        float4 p; p.x = x; p.y = y; p.z = z;
        p.w = (x*x + y*y) + z*z;
        ((float4*)(wsf + OFF_PTS4/4))[n] = p;
    }
}

// ---------------- kernel 2: per-query threshold tau ----------------
// tau[q] = (20th-largest of union(8 per-thread top-6) over candidates [0,1024)) - margin.
// union-20th <= subset-20th <= full-20th, and the 5e-4 margin covers all screening-score
// vs np-f32-pd discrepancies (<= ~3e-5) -> bitmap survivors are a superset of np's top-20.
__global__ __launch_bounds__(256) void ktau(const float* __restrict__ wsf, float* __restrict__ tau)
{
    const float4* pts4 = (const float4*)(wsf + OFF_PTS4/4);
    __shared__ float t6[32][8][6];
    const int tid = threadIdx.x;
    const int ql = tid >> 3, t = tid & 7;
    const int q = blockIdx.x*32 + ql;
    float4 qp = pts4[q];
    float qx2 = qp.x + qp.x, qy2 = qp.y + qp.y, qz2 = qp.z + qp.z;
    float v0 = NEG_INF, v1 = NEG_INF, v2 = NEG_INF, v3 = NEG_INF, v4 = NEG_INF, v5 = NEG_INF;
    const int jb = t*128;
    for (int i = 0; i < 128; ++i) {
        float v = pd_score(qx2, qy2, qz2, pts4[jb + i]);
        float n5 = v > v5 ? (v > v4 ? v4 : v) : v5;
        float n4 = v > v4 ? (v > v3 ? v3 : v) : v4;
        float n3 = v > v3 ? (v > v2 ? v2 : v) : v3;
        float n2 = v > v2 ? (v > v1 ? v1 : v) : v2;
        float n1 = v > v1 ? (v > v0 ? v0 : v) : v1;
        float n0 = v > v0 ? v : v0;
        v0 = n0; v1 = n1; v2 = n2; v3 = n3; v4 = n4; v5 = n5;
    }
    t6[ql][t][0] = v0; t6[ql][t][1] = v1; t6[ql][t][2] = v2;
    t6[ql][t][3] = v3; t6[ql][t][4] = v4; t6[ql][t][5] = v5;
    __syncthreads();
    if (t == 0) {
        int p0=0,p1=0,p2=0,p3=0,p4=0,p5=0,p6=0,p7=0;
        float last = NEG_INF;
        for (int it = 0; it < 20; ++it) {
            float best = NEG_INF; int bl = -1;
#define CHK(L, PL) { float h = t6[ql][L][(PL) < 6 ? (PL) : 5]; if (((PL) < 6) && (h > best)) { best = h; bl = L; } }
            CHK(0,p0) CHK(1,p1) CHK(2,p2) CHK(3,p3) CHK(4,p4) CHK(5,p5) CHK(6,p6) CHK(7,p7)
#undef CHK
            p0 += (bl==0); p1 += (bl==1); p2 += (bl==2); p3 += (bl==3);
            p4 += (bl==4); p5 += (bl==5); p6 += (bl==6); p7 += (bl==7);
            last = best;
        }
        tau[q] = last - 5e-4f;   // conservative margin (covers fmaf-chain vs np-f32 rounding)
    }
}

// ---------------- kernel 3: streaming scan -> survivor BITMAP (round-12 proven) -----
// Measured 61.7us; 4 alternatives all regressed (91/165/97us) -> keep frozen.
__global__ __launch_bounds__(256) void kpush(const float* __restrict__ wsf,
                                             const float* __restrict__ tau,
                                             unsigned* __restrict__ bm)
{
    const float4* pts4 = (const float4*)(wsf + OFF_PTS4/4);
    __shared__ uint4 st[256][5];   // 20KB; slot [tid][g], pad 5 -> stride 20 words
    const int qg = blockIdx.x >> 5, c = blockIdx.x & 31;
    const int tid = threadIdx.x;
    const int jbase = c * 512;
    const int q = qg*256 + tid;
    float4 a = pts4[q];
    float ax2 = a.x + a.x, ay2 = a.y + a.y, az2 = a.z + a.z;
    float nt0 = -tau[q];
    for (int g = 0; g < 4; ++g) {
        unsigned wd[4];
#pragma unroll
        for (int u = 0; u < 4; ++u) {
            const int base = jbase + (g*4 + u)*32;
            unsigned w = 0u;
#pragma unroll
            for (int k = 0; k < 32; k += 4) {
                float4 d0 = pts4[base + k];
                float4 d1 = pts4[base + k + 1];
                float4 d2 = pts4[base + k + 2];
                float4 d3 = pts4[base + k + 3];
                float s0 = fmaf(az2, d0.z, fmaf(ay2, d0.y, fmaf(ax2, d0.x, nt0)));
                float s1 = fmaf(az2, d1.z, fmaf(ay2, d1.y, fmaf(ax2, d1.x, nt0)));
                float s2 = fmaf(az2, d2.z, fmaf(ay2, d2.y, fmaf(ax2, d2.x, nt0)));
                float s3 = fmaf(az2, d3.z, fmaf(ay2, d3.y, fmaf(ax2, d3.x, nt0)));
                w |= (s0 >= d0.w) ? (1u << k)       : 0u;
                w |= (s1 >= d1.w) ? (1u << (k + 1)) : 0u;
                w |= (s2 >= d2.w) ? (1u << (k + 2)) : 0u;
                w |= (s3 >= d3.w) ? (1u << (k + 3)) : 0u;
            }
            wd[u] = w;
        }
        uint4 o; o.x = wd[0]; o.y = wd[1]; o.z = wd[2]; o.w = wd[3];
        st[tid][g] = o;
    }
    uint4* dst = (uint4*)(bm + (size_t)q*512 + c*16);
#pragma unroll
    for (int g = 0; g < 4; ++g) dst[g] = st[tid][g];
}

// ---------------- kernel 4: exact top-20 from bitmap — balanced pool-and-rank -------
#define KS(A,B) V##A = (kk > V##B) ? V##B : ((kk > V##A) ? kk : V##A);
__global__ __launch_bounds__(256) void ksel(const float* __restrict__ wsf,
                                            const unsigned* __restrict__ bm,
                                            unsigned* __restrict__ knn)
{
    #pragma clang fp contract(off)
    const float4* pts4 = (const float4*)(wsf + OFF_PTS4/4);
    __shared__ unsigned short spool[4][1024];
    __shared__ unsigned long long pool[4][128];
    const int lane = threadIdx.x & 63;
    const int qw   = threadIdx.x >> 6;
    const int q = blockIdx.x*4 + qw;
    float4 qp = pts4[q];

    // ---- stage A: balanced survivor-index extraction ----
    const uint4* row = (const uint4*)(bm + (size_t)q*512) + lane*2;
    uint4 a0 = row[0], a1 = row[1];
    unsigned wv[8] = {a0.x, a0.y, a0.z, a0.w, a1.x, a1.y, a1.z, a1.w};
    int scnt = 0;
#pragma unroll
    for (int t = 0; t < 8; ++t) scnt += __popc(wv[t]);
    int spre = scnt;
#pragma unroll
    for (int o = 1; o < 64; o <<= 1) {
        int t2 = __shfl_up(spre, o, 64);
        spre += (lane >= o) ? t2 : 0;
    }
    int nS = __shfl(spre, 63, 64);
    if (nS > 1024) nS = 1024;
    unsigned short* sp = spool[qw];
    int wptr = spre - scnt;
#pragma unroll
    for (int t = 0; t < 8; ++t) {
        unsigned w = wv[t];
        const int wbase = (lane*8 + t)*32;
        while (w) {
            int b = __ffs(w) - 1; w &= w - 1;
            if (wptr < 1024) sp[wptr] = (unsigned short)(wbase + b);
            ++wptr;
        }
    }
    __syncthreads();

    // ---- stage B: uniform round-robin scoring into register top-8 ----
    unsigned long long V0=0,V1=0,V2=0,V3=0,V4=0,V5=0,V6=0,V7=0;
    const int rounds = (nS + 63) >> 6;
    for (int r = 0; r < rounds; ++r) {
        int i = r*64 + lane;
        bool val = i < nS;
        int j = val ? (int)sp[i] : 0;
        float4 cp = pts4[j];
        float d  = (qp.x*cp.x + qp.y*cp.y) + qp.z*cp.z;
        float pd = (2.0f*d - qp.w) - cp.w;
        unsigned long long kk = val ? (((unsigned long long)sortable_f(pd) << 14)
                                      | (unsigned long long)(16383 - j)) : 0ull;
        if (kk > V7) {
            KS(7,6) KS(6,5) KS(5,4) KS(4,3) KS(3,2) KS(2,1) KS(1,0)
            V0 = (kk > V0) ? kk : V0;
        }
    }

    // ---- bitonic ascending sort of lane maxima; theta at lane 44 (20th largest) ----
    unsigned long long ss = V0;
#pragma unroll
    for (int k = 2; k <= 64; k <<= 1) {
#pragma unroll
        for (int j = k >> 1; j > 0; j >>= 1) {
            unsigned long long o = __shfl_xor(ss, j, 64);
            bool up = ((lane & k) == 0);
            bool lower = ((lane & j) == 0);
            ss = (lower == up) ? ((ss < o) ? ss : o) : ((ss > o) ? ss : o);
        }
    }
    unsigned long long theta = __shfl(ss, 44, 64);

    // ---- compact kept keys >= theta into u64 LDS pool ----
    int kcnt = (int)(V0 >= theta) + (int)(V1 >= theta) + (int)(V2 >= theta)
             + (int)(V3 >= theta) + (int)(V4 >= theta) + (int)(V5 >= theta)
             + (int)(V6 >= theta) + (int)(V7 >= theta);
    int ksc = kcnt;
#pragma unroll
    for (int o = 1; o < 64; o <<= 1) {
        int t2 = __shfl_up(ksc, o, 64);
        ksc += (lane >= o) ? t2 : 0;
    }
    int C = __shfl(ksc, 63, 64);
    int kbase = ksc - kcnt;
    if (C > 128) C = 128;
    unsigned long long* pq = pool[qw];
#define WPOOL(I, VI) if (I < kcnt) { int p = kbase + I; if (p < 128) pq[p] = VI; }
    WPOOL(0, V0) WPOOL(1, V1) WPOOL(2, V2) WPOOL(3, V3)
    WPOOL(4, V4) WPOOL(5, V5) WPOOL(6, V6) WPOOL(7, V7)
#undef WPOOL
    __syncthreads();

    // ---- rank by counting greater pool keys (broadcast LDS reads) ----
    bool h1 = lane < C;
    bool h2 = (lane + 64) < C;
    unsigned long long k1 = h1 ? pq[lane] : 0ull;
    unsigned long long k2 = h2 ? pq[lane + 64] : 0ull;
    int r1 = 0, r2 = 0;
    for (int i = 0; i < C; ++i) {
        unsigned long long ki = pq[i];
        r1 += (int)(ki > k1);
        r2 += (int)(ki > k2);
    }
    unsigned* kout = knn + (size_t)q*20;
    if (h1 && r1 < 20) kout[r1] = 16383u - (unsigned)(k1 & 0x3FFFull);
    if (h2 && r2 < 20) kout[r2] = 16383u - (unsigned)(k2 & 0x3FFFull);
}

// ---------------- kernel 5: GEMM for feature part of G and T2 (32-n tiles) ----------
// Round-17 audit: 256 blocks x 128 thr = 1 block/CU, 2 waves/CU -> latency-exposed.
// Retile: 32-n x 128-o, grid 512, 256 thr (16 tx x 16 ty), acc 2x8, LDS 20KB
// -> 2 blocks/CU x 4 waves = 8 waves/CU (4x latency hiding). Same output mapping.
__global__ __launch_bounds__(256) void kgemm(const float* __restrict__ feat,
                                             const float* __restrict__ wsf,
                                             float* __restrict__ G, float* __restrict__ T2)
{
    __shared__ float As[32][32];
    __shared__ float Bs[32][128];
    const float* WKC = wsf + OFF_WKC/4;
    const float* CBF = wsf + OFF_CBF/4;
    const int tid = threadIdx.x;
    const int n0 = blockIdx.x * 32;
    const int tx = tid & 15, ty = tid >> 4;
    float acc[2][8] = {};
    for (int kc = 0; kc < 4; ++kc) {
        int c0 = kc * 32;
        for (int i = tid; i < 1024; i += 256) {
            int cl = i >> 5, nl = i & 31;
            As[cl][nl] = feat[(size_t)(c0 + cl)*NPT + n0 + nl];
        }
        for (int i = tid; i < 4096; i += 256) {
            int cl = i >> 7, ol = i & 127;
            Bs[cl][ol] = WKC[(c0 + cl)*128 + ol];
        }
        __syncthreads();
        for (int cc = 0; cc < 32; ++cc) {
            float av[2], bv[8];
#pragma unroll
            for (int r = 0; r < 2; ++r) av[r] = As[cc][ty*2 + r];
#pragma unroll
            for (int s = 0; s < 8; ++s) bv[s] = Bs[cc][tx*8 + s];
#pragma unroll
            for (int r = 0; r < 2; ++r)
#pragma unroll
                for (int s = 0; s < 8; ++s)
                    acc[r][s] = fmaf(av[r], bv[s], acc[r][s]);
        }
        __syncthreads();
    }
#pragma unroll
    for (int r = 0; r < 2; ++r) {
        int n = n0 + ty*2 + r;
        if (tx < 8) {
            float* dst = G + (size_t)n*128 + 64 + tx*8;
#pragma unroll
            for (int s = 0; s < 8; ++s) dst[s] = acc[r][s];
        } else {
            int ob = (tx - 8)*8;
            float* dst = T2 + (size_t)n*128 + 64 + ob;
#pragma unroll
            for (int s = 0; s < 8; ++s) dst[s] = acc[r][s] + CBF[ob + s];
        }
    }
}

// ---------------- kernel 6: xyz part of G and T2 ----------------
__global__ __launch_bounds__(256) void kxpart(const float* __restrict__ xyz,
                                              const float* __restrict__ wsf,
                                              float* __restrict__ G, float* __restrict__ T2)
{
    const float4* WAX = (const float4*)(wsf + OFF_WAX/4);
    const float4* WBX = (const float4*)(wsf + OFF_WBX/4);
    const float*  CBX = wsf + OFF_CBX/4;
    const int tid = threadIdx.x;
    const int o = tid & 63;
    const int n = blockIdx.x*4 + (tid >> 6);
    float x = xyz[n], y = xyz[NPT+n], z = xyz[2*NPT+n];
    float4 A = WAX[o], B = WBX[o];
    G[(size_t)n*128 + o]  = fmaf(x, A.x, fmaf(y, A.y, z*A.z));
    T2[(size_t)n*128 + o] = fmaf(x, B.x, fmaf(y, B.y, fmaf(z, B.z, CBX[o])));
}

// ---------------- kernel 7: gather + max-pool + f1/f2 + partials (32-n tiles) -------
// Round-17 audit: 256 blocks = 1/CU, 4 waves/CU, L2-gather latency exposed. Retile to
// 32 n/block (grid 512, 8 lanes/row -> full 512B G-row gathers coalesced per nl-group),
// LDS ~38KB -> 2 blocks/CU x 4 waves = 8 waves/CU. PART partials (512x16) go to the
// dead TAU region; kch sums 512 blocks.
__global__ __launch_bounds__(256) void kgather(const float* __restrict__ wsf,
                                               const unsigned* __restrict__ knn,
                                               const float* __restrict__ G,
                                               const float* __restrict__ T2,
                                               const float* __restrict__ wd1,
                                               const float* __restrict__ wd2,
                                               float* __restrict__ F, float* __restrict__ F1,
                                               float* __restrict__ F2, float* __restrict__ SPm,
                                               float* __restrict__ PART)
{
    __shared__ float fsh[32][136];
    __shared__ float w1s[16][136];
    __shared__ float w2s[16][136];
    __shared__ float f1sh[32][16];
    __shared__ float f2p[32][8];
    const int tid = threadIdx.x;
    for (int i = tid; i < 2048; i += 256) {
        int o = i >> 7, cc = i & 127;
        w1s[o][cc] = wd1[i];
        w2s[o][cc] = wd2[i];
    }
    const int nl = tid >> 3, qt = tid & 7;   // 32 rows x 8 channel-groups of 16
    const int n = blockIdx.x*32 + nl;
    const unsigned* ip = knn + (size_t)n*20;
    float acc[16];
#pragma unroll
    for (int e = 0; e < 16; ++e) acc[e] = NEG_INF;
    for (int k = 0; k < 20; ++k) {
        unsigned j = ip[k];
        const float4* g4 = (const float4*)(G + (size_t)j*128 + qt*16);
#pragma unroll
        for (int r = 0; r < 4; ++r) {
            float4 gv = g4[r];
            acc[r*4+0] = fmaxf(acc[r*4+0], gv.x);
            acc[r*4+1] = fmaxf(acc[r*4+1], gv.y);
            acc[r*4+2] = fmaxf(acc[r*4+2], gv.z);
            acc[r*4+3] = fmaxf(acc[r*4+3], gv.w);
        }
    }
    const float4* t4 = (const float4*)(T2 + (size_t)n*128 + qt*16);
    float4* fg = (float4*)(F + (size_t)n*128 + qt*16);
    float4* fs = (float4*)&fsh[nl][qt*16];
#pragma unroll
    for (int r = 0; r < 4; ++r) {
        float4 tv = t4[r];
        float4 o4;
        o4.x = fmaxf(acc[r*4+0] + tv.x, 0.f);
        o4.y = fmaxf(acc[r*4+1] + tv.y, 0.f);
        o4.z = fmaxf(acc[r*4+2] + tv.z, 0.f);
        o4.w = fmaxf(acc[r*4+3] + tv.w, 0.f);
        fg[r] = o4; fs[r] = o4;
    }
    __syncthreads();
    // phase 2: f1/f2 (2 outputs each per thread; ob = qt*2)
    float a1[2] = {0,0}, a2[2] = {0,0};
    const int ob = qt*2;
    for (int c4 = 0; c4 < 32; ++c4) {
        float4 fv = ((const float4*)&fsh[nl][0])[c4];
#pragma unroll
        for (int r = 0; r < 2; ++r) {
            float4 wv1 = ((const float4*)&w1s[ob + r][0])[c4];
            float4 wv2 = ((const float4*)&w2s[ob + r][0])[c4];
            a1[r] = fmaf(fv.x, wv1.x, fmaf(fv.y, wv1.y, fmaf(fv.z, wv1.z, fmaf(fv.w, wv1.w, a1[r]))));
            a2[r] = fmaf(fv.x, wv2.x, fmaf(fv.y, wv2.y, fmaf(fv.z, wv2.z, fmaf(fv.w, wv2.w, a2[r]))));
        }
    }
    float s2sum = 0.f;
#pragma unroll
    for (int r = 0; r < 2; ++r) {
        a1[r] = fmaxf(a1[r], 0.f);
        a2[r] = fmaxf(a2[r], 0.f);
        s2sum += a2[r];
        F1[(size_t)n*16 + ob + r] = a1[r];
        F2[(size_t)n*16 + ob + r] = a2[r];
        f1sh[nl][ob + r] = a1[r];
    }
    f2p[nl][qt] = s2sum;
    __syncthreads();
    if (qt == 0) {
        float s = 0.f;
#pragma unroll
        for (int t = 0; t < 8; ++t) s += f2p[nl][t];
        SPm[n] = s * (1.0f/16.0f);
    }
    if (tid < 16) {
        float s = 0.f;
        for (int r = 0; r < 32; ++r) s += f1sh[r][tid];
        PART[blockIdx.x*16 + tid] = s;
    }
}

// ---------------- kernel 8: reduce channel mean (512 partials) ----------------
__global__ __launch_bounds__(64) void kch(const float* __restrict__ PART, float* __restrict__ CH)
{
    const int tid = threadIdx.x;
    if (tid < 16) {
        float s = 0.f;
        for (int b = 0; b < 512; ++b) s += PART[b*16 + tid];
        CH[tid] = s * (1.0f/16384.0f);
    }
}

// ---------------- kernel 9: final head + mish + transpose (4 thr/point) -------------
// Round-17 audit: 64-thr blocks = 1 wave/CU. Now 256 thr: nl = tid>>2 (64 points),
// qt = tid&3 (o-quarter of 32 outputs); fin[16] recomputed per thread (cheap)
// -> 4 waves/CU, 4x less serial work per thread.
__global__ __launch_bounds__(256) void kfinal(const float* __restrict__ wsf,
                                              const float* __restrict__ F,
                                              const float* __restrict__ F1,
                                              const float* __restrict__ F2,
                                              const float* __restrict__ SPm,
                                              const float* __restrict__ CH,
                                              float* __restrict__ out)
{
    const float* WUP = wsf + OFF_WUP/4;
    const float* BUP = wsf + OFF_BUP/4;
    const int tid = threadIdx.x;
    const int nl = tid >> 2, qt = tid & 3;
    const int n = blockIdx.x*64 + nl;
    float spv = SPm[n];
    float fin[16];
    const float4* f14 = (const float4*)(F1 + (size_t)n*16);
    const float4* f24 = (const float4*)(F2 + (size_t)n*16);
#pragma unroll
    for (int c4 = 0; c4 < 4; ++c4) {
        float4 a = f14[c4], b = f24[c4];
        fin[c4*4+0] = sqrtf(fmaf(CH[c4*4+0], spv, 1e-12f)) + a.x + b.x;
        fin[c4*4+1] = sqrtf(fmaf(CH[c4*4+1], spv, 1e-12f)) + a.y + b.y;
        fin[c4*4+2] = sqrtf(fmaf(CH[c4*4+2], spv, 1e-12f)) + a.z + b.z;
        fin[c4*4+3] = sqrtf(fmaf(CH[c4*4+3], spv, 1e-12f)) + a.w + b.w;
    }
    const float4* fF = (const float4*)(F + (size_t)n*128);
    for (int o4 = qt*8; o4 < qt*8 + 8; ++o4) {
        float4 fv = fF[o4];
        float fa[4] = {fv.x, fv.y, fv.z, fv.w};
#pragma unroll
        for (int e = 0; e < 4; ++e) {
            int o = o4*4 + e;
            float u = BUP[o];
#pragma unroll
            for (int c = 0; c < 16; ++c) u = fmaf(fin[c], WUP[o*16 + c], u);
            u = fmaxf(u, 0.f);
            float fl = fa[e] - u;
            // mish: fl * tanh(softplus(fl)) ; tanh(log1p(e^x)) = ((1+e^x)^2-1)/((1+e^x)^2+1)
            float flc = fminf(fl, 15.f);
            float t = expf(flc);
            float w = 1.f + t;
            float w2 = w*w;
            float th = (w2 - 1.f) / (w2 + 1.f);
            float res = (fl > 15.f) ? fl : fl * th;
            out[(size_t)o*NPT + n] = res;
        }
    }
}

extern "C" void kernel_launch(void* const* d_in, const int* in_sizes, int n_in,
                              void* d_out, int out_size, void* d_ws, size_t ws_size,
                              hipStream_t stream) {
    const float* xyz  = (const float*)d_in[0];
    const float* feat = (const float*)d_in[1];
    const float* w1   = (const float*)d_in[2];
    const float* b1   = (const float*)d_in[3];
    const float* g1   = (const float*)d_in[4];
    const float* bb1  = (const float*)d_in[5];
    const float* m1   = (const float*)d_in[6];
    const float* v1   = (const float*)d_in[7];
    const float* w2   = (const float*)d_in[8];
    const float* b2   = (const float*)d_in[9];
    const float* g2   = (const float*)d_in[10];
    const float* bb2  = (const float*)d_in[11];
    const float* m2   = (const float*)d_in[12];
    const float* v2   = (const float*)d_in[13];
    const float* wd1  = (const float*)d_in[14];
    const float* wd2  = (const float*)d_in[15];
    const float* wup  = (const float*)d_in[16];
    const float* bup  = (const float*)d_in[17];
    const float* gu   = (const float*)d_in[18];
    const float* bu2  = (const float*)d_in[19];
    const float* mu   = (const float*)d_in[20];
    const float* vu   = (const float*)d_in[21];
    float* out = (float*)d_out;

    float* wsf = (float*)d_ws;
    unsigned* bm   = (unsigned*)((char*)d_ws + OFF_R);
    unsigned* knn  = (unsigned*)((char*)d_ws + OFF_KNN);
    float* TAU  = (float*)((char*)d_ws + OFF_TAU);
    float* PART = (float*)((char*)d_ws + OFF_TAU);   // TAU region dead after kpush
    float* CH   = (float*)((char*)d_ws + OFF_CH);
    // region R reused after ksel
    float* G  = (float*)((char*)d_ws + OFF_R);
    float* T2 = G  + 2097152;
    float* F  = T2 + 2097152;
    float* F1 = F  + 2097152;
    float* F2 = F1 + 262144;
    float* SPm = F2 + 262144;

    kprep<<<dim3(65),  dim3(256), 0, stream>>>(xyz, w1,b1,g1,bb1,m1,v1,
                                               w2,b2,g2,bb2,m2,v2,
                                               wup,bup,gu,bu2,mu,vu, wsf);
    ktau <<<dim3(512), dim3(256), 0, stream>>>(wsf, TAU);
    kpush<<<dim3(2048), dim3(256), 0, stream>>>(wsf, TAU, bm);
    ksel <<<dim3(4096), dim3(256), 0, stream>>>(wsf, bm, knn);
    kgemm<<<dim3(512), dim3(256), 0, stream>>>(feat, wsf, G, T2);
    kxpart<<<dim3(4096), dim3(256), 0, stream>>>(xyz, wsf, G, T2);
    kgather<<<dim3(512), dim3(256), 0, stream>>>(wsf, knn, G, T2, wd1, wd2, F, F1, F2, SPm, PART);
    kch  <<<dim3(1),   dim3(64), 0, stream>>>(PART, CH);
    kfinal<<<dim3(256), dim3(256), 0, stream>>>(wsf, F, F1, F2, SPm, CH, out);
}

// Round 19
// 215.246 us; speedup vs baseline: 1.5545x; 1.0213x over previous
//
#include <hip/hip_runtime.h>

#define NPT 16384
#define NEG_INF (-3.402823466e38f)

// ---- workspace byte offsets ----
#define OFF_PTS4  0u            // 16384 * 16          = 262144
#define OFF_WKC   262144u       // 128*128*4           = 65536
#define OFF_WAX   327680u       // 64*4*4              = 1024
#define OFF_WBX   328704u       // 1024
#define OFF_CBX   329728u       // 256
#define OFF_CBF   329984u       // 256
#define OFF_WUP   330240u       // 128*16*4            = 8192
#define OFF_BUP   338432u       // 512
#define OFF_TAU   338944u       // 16384*4 = 65536; DEAD after kpush -> reused as PART(512*16*4=32KB)
#define OFF_KNN   666624u       // 16384*20*4          = 1310720
#define OFF_CH    1993728u      // 256
#define OFF_R     1994240u      // reused: survivor bitmap u32[16384][512] = 33554432
                                // after ksel: Gb bf16(4MB), T2(8MB), F(8MB), F1(1MB), F2(1MB), SPm(64KB)

__device__ __forceinline__ float pd_score(float qx2, float qy2, float qz2, float4 c) {
    return fmaf(qx2, c.x, fmaf(qy2, c.y, fmaf(qz2, c.z, -c.w)));
}

__device__ __forceinline__ unsigned sortable_f(float v) {
    unsigned b = __float_as_uint(v);
    return (b & 0x80000000u) ? ~b : (b | 0x80000000u);
}

// bf16 round-to-nearest-even pack
__device__ __forceinline__ unsigned short f2bf(float f) {
    unsigned b = __float_as_uint(f);
    return (unsigned short)((b + 0x7FFFu + ((b >> 16) & 1u)) >> 16);
}
#define BF2F_LO(w) __uint_as_float((w) << 16)
#define BF2F_HI(w) __uint_as_float((w) & 0xFFFF0000u)

// ---------------- kernel 1: weight folds + pts4 ----------------
__global__ __launch_bounds__(256) void kprep(
    const float* __restrict__ xyz,
    const float* __restrict__ w1, const float* __restrict__ b1,
    const float* __restrict__ g1, const float* __restrict__ bb1,
    const float* __restrict__ m1, const float* __restrict__ v1,
    const float* __restrict__ w2, const float* __restrict__ b2,
    const float* __restrict__ g2, const float* __restrict__ bb2,
    const float* __restrict__ m2, const float* __restrict__ v2,
    const float* __restrict__ wup, const float* __restrict__ bup,
    const float* __restrict__ gu, const float* __restrict__ bu2,
    const float* __restrict__ mu, const float* __restrict__ vu,
    float* __restrict__ wsf)
{
    const int tid = threadIdx.x;
    if (blockIdx.x == 0) {
        float* WKC = wsf + OFF_WKC/4;
        float* WAX = wsf + OFF_WAX/4;
        float* WBX = wsf + OFF_WBX/4;
        float* CBX = wsf + OFF_CBX/4;
        float* CBF = wsf + OFF_CBF/4;
        float* WUP = wsf + OFF_WUP/4;
        float* BUP = wsf + OFF_BUP/4;
        for (int i = tid; i < 16384; i += 256) {
            int c = i >> 7, o = i & 127, oo = o & 63;
            float s2 = g2[oo] * rsqrtf(v2[oo] + 1e-5f);
            float val = (o < 64) ? s2 * w2[oo*256 + c]
                                 : s2 * (w2[oo*256 + 128 + c] - w2[oo*256 + c]);
            WKC[c*128 + o] = val;
        }
        if (tid < 64) {
            int o = tid;
            float s1 = g1[o] * rsqrtf(v1[o] + 1e-5f);
            WAX[o*4+0] = s1 * w1[o*6+0];
            WAX[o*4+1] = s1 * w1[o*6+1];
            WAX[o*4+2] = s1 * w1[o*6+2];
            WAX[o*4+3] = 0.f;
            WBX[o*4+0] = s1 * (w1[o*6+3] - w1[o*6+0]);
            WBX[o*4+1] = s1 * (w1[o*6+4] - w1[o*6+1]);
            WBX[o*4+2] = s1 * (w1[o*6+5] - w1[o*6+2]);
            WBX[o*4+3] = 0.f;
            CBX[o] = s1 * b1[o] + (bb1[o] - m1[o]*s1);
            float s2b = g2[o] * rsqrtf(v2[o] + 1e-5f);
            CBF[o] = s2b * b2[o] + (bb2[o] - m2[o]*s2b);
        }
        if (tid < 128) {
            int o = tid;
            float su = gu[o] * rsqrtf(vu[o] + 1e-5f);
            for (int c = 0; c < 16; ++c) WUP[o*16+c] = su * wup[o*16+c];
            BUP[o] = su * bup[o] + (bu2[o] - mu[o]*su);
        }
    } else {
        #pragma clang fp contract(off)
        int n = (blockIdx.x - 1)*256 + tid;
        float x = xyz[n], y = xyz[NPT+n], z = xyz[2*NPT+n];
        float4 p; p.x = x; p.y = y; p.z = z;
        p.w = (x*x + y*y) + z*z;
        ((float4*)(wsf + OFF_PTS4/4))[n] = p;
    }
}

// ---------------- kernel 2: per-query threshold tau ----------------
__global__ __launch_bounds__(256) void ktau(const float* __restrict__ wsf, float* __restrict__ tau)
{
    const float4* pts4 = (const float4*)(wsf + OFF_PTS4/4);
    __shared__ float t6[32][8][6];
    const int tid = threadIdx.x;
    const int ql = tid >> 3, t = tid & 7;
    const int q = blockIdx.x*32 + ql;
    float4 qp = pts4[q];
    float qx2 = qp.x + qp.x, qy2 = qp.y + qp.y, qz2 = qp.z + qp.z;
    float v0 = NEG_INF, v1 = NEG_INF, v2 = NEG_INF, v3 = NEG_INF, v4 = NEG_INF, v5 = NEG_INF;
    const int jb = t*128;
    for (int i = 0; i < 128; ++i) {
        float v = pd_score(qx2, qy2, qz2, pts4[jb + i]);
        float n5 = v > v5 ? (v > v4 ? v4 : v) : v5;
        float n4 = v > v4 ? (v > v3 ? v3 : v) : v4;
        float n3 = v > v3 ? (v > v2 ? v2 : v) : v3;
        float n2 = v > v2 ? (v > v1 ? v1 : v) : v2;
        float n1 = v > v1 ? (v > v0 ? v0 : v) : v1;
        float n0 = v > v0 ? v : v0;
        v0 = n0; v1 = n1; v2 = n2; v3 = n3; v4 = n4; v5 = n5;
    }
    t6[ql][t][0] = v0; t6[ql][t][1] = v1; t6[ql][t][2] = v2;
    t6[ql][t][3] = v3; t6[ql][t][4] = v4; t6[ql][t][5] = v5;
    __syncthreads();
    if (t == 0) {
        int p0=0,p1=0,p2=0,p3=0,p4=0,p5=0,p6=0,p7=0;
        float last = NEG_INF;
        for (int it = 0; it < 20; ++it) {
            float best = NEG_INF; int bl = -1;
#define CHK(L, PL) { float h = t6[ql][L][(PL) < 6 ? (PL) : 5]; if (((PL) < 6) && (h > best)) { best = h; bl = L; } }
            CHK(0,p0) CHK(1,p1) CHK(2,p2) CHK(3,p3) CHK(4,p4) CHK(5,p5) CHK(6,p6) CHK(7,p7)
#undef CHK
            p0 += (bl==0); p1 += (bl==1); p2 += (bl==2); p3 += (bl==3);
            p4 += (bl==4); p5 += (bl==5); p6 += (bl==6); p7 += (bl==7);
            last = best;
        }
        tau[q] = last - 5e-4f;
    }
}

// ---------------- kernel 3: streaming scan -> survivor BITMAP (round-12 frozen) -----
__global__ __launch_bounds__(256) void kpush(const float* __restrict__ wsf,
                                             const float* __restrict__ tau,
                                             unsigned* __restrict__ bm)
{
    const float4* pts4 = (const float4*)(wsf + OFF_PTS4/4);
    __shared__ uint4 st[256][5];
    const int qg = blockIdx.x >> 5, c = blockIdx.x & 31;
    const int tid = threadIdx.x;
    const int jbase = c * 512;
    const int q = qg*256 + tid;
    float4 a = pts4[q];
    float ax2 = a.x + a.x, ay2 = a.y + a.y, az2 = a.z + a.z;
    float nt0 = -tau[q];
    for (int g = 0; g < 4; ++g) {
        unsigned wd[4];
#pragma unroll
        for (int u = 0; u < 4; ++u) {
            const int base = jbase + (g*4 + u)*32;
            unsigned w = 0u;
#pragma unroll
            for (int k = 0; k < 32; k += 4) {
                float4 d0 = pts4[base + k];
                float4 d1 = pts4[base + k + 1];
                float4 d2 = pts4[base + k + 2];
                float4 d3 = pts4[base + k + 3];
                float s0 = fmaf(az2, d0.z, fmaf(ay2, d0.y, fmaf(ax2, d0.x, nt0)));
                float s1 = fmaf(az2, d1.z, fmaf(ay2, d1.y, fmaf(ax2, d1.x, nt0)));
                float s2 = fmaf(az2, d2.z, fmaf(ay2, d2.y, fmaf(ax2, d2.x, nt0)));
                float s3 = fmaf(az2, d3.z, fmaf(ay2, d3.y, fmaf(ax2, d3.x, nt0)));
                w |= (s0 >= d0.w) ? (1u << k)       : 0u;
                w |= (s1 >= d1.w) ? (1u << (k + 1)) : 0u;
                w |= (s2 >= d2.w) ? (1u << (k + 2)) : 0u;
                w |= (s3 >= d3.w) ? (1u << (k + 3)) : 0u;
            }
            wd[u] = w;
        }
        uint4 o; o.x = wd[0]; o.y = wd[1]; o.z = wd[2]; o.w = wd[3];
        st[tid][g] = o;
    }
    uint4* dst = (uint4*)(bm + (size_t)q*512 + c*16);
#pragma unroll
    for (int g = 0; g < 4; ++g) dst[g] = st[tid][g];
}

// ---------------- kernel 4: exact top-20 from bitmap — balanced pool-and-rank -------
#define KS(A,B) V##A = (kk > V##B) ? V##B : ((kk > V##A) ? kk : V##A);
__global__ __launch_bounds__(256) void ksel(const float* __restrict__ wsf,
                                            const unsigned* __restrict__ bm,
                                            unsigned* __restrict__ knn)
{
    #pragma clang fp contract(off)
    const float4* pts4 = (const float4*)(wsf + OFF_PTS4/4);
    __shared__ unsigned short spool[4][1024];
    __shared__ unsigned long long pool[4][128];
    const int lane = threadIdx.x & 63;
    const int qw   = threadIdx.x >> 6;
    const int q = blockIdx.x*4 + qw;
    float4 qp = pts4[q];

    const uint4* row = (const uint4*)(bm + (size_t)q*512) + lane*2;
    uint4 a0 = row[0], a1 = row[1];
    unsigned wv[8] = {a0.x, a0.y, a0.z, a0.w, a1.x, a1.y, a1.z, a1.w};
    int scnt = 0;
#pragma unroll
    for (int t = 0; t < 8; ++t) scnt += __popc(wv[t]);
    int spre = scnt;
#pragma unroll
    for (int o = 1; o < 64; o <<= 1) {
        int t2 = __shfl_up(spre, o, 64);
        spre += (lane >= o) ? t2 : 0;
    }
    int nS = __shfl(spre, 63, 64);
    if (nS > 1024) nS = 1024;
    unsigned short* sp = spool[qw];
    int wptr = spre - scnt;
#pragma unroll
    for (int t = 0; t < 8; ++t) {
        unsigned w = wv[t];
        const int wbase = (lane*8 + t)*32;
        while (w) {
            int b = __ffs(w) - 1; w &= w - 1;
            if (wptr < 1024) sp[wptr] = (unsigned short)(wbase + b);
            ++wptr;
        }
    }
    __syncthreads();

    unsigned long long V0=0,V1=0,V2=0,V3=0,V4=0,V5=0,V6=0,V7=0;
    const int rounds = (nS + 63) >> 6;
    for (int r = 0; r < rounds; ++r) {
        int i = r*64 + lane;
        bool val = i < nS;
        int j = val ? (int)sp[i] : 0;
        float4 cp = pts4[j];
        float d  = (qp.x*cp.x + qp.y*cp.y) + qp.z*cp.z;
        float pd = (2.0f*d - qp.w) - cp.w;
        unsigned long long kk = val ? (((unsigned long long)sortable_f(pd) << 14)
                                      | (unsigned long long)(16383 - j)) : 0ull;
        if (kk > V7) {
            KS(7,6) KS(6,5) KS(5,4) KS(4,3) KS(3,2) KS(2,1) KS(1,0)
            V0 = (kk > V0) ? kk : V0;
        }
    }

    unsigned long long ss = V0;
#pragma unroll
    for (int k = 2; k <= 64; k <<= 1) {
#pragma unroll
        for (int j = k >> 1; j > 0; j >>= 1) {
            unsigned long long o = __shfl_xor(ss, j, 64);
            bool up = ((lane & k) == 0);
            bool lower = ((lane & j) == 0);
            ss = (lower == up) ? ((ss < o) ? ss : o) : ((ss > o) ? ss : o);
        }
    }
    unsigned long long theta = __shfl(ss, 44, 64);

    int kcnt = (int)(V0 >= theta) + (int)(V1 >= theta) + (int)(V2 >= theta)
             + (int)(V3 >= theta) + (int)(V4 >= theta) + (int)(V5 >= theta)
             + (int)(V6 >= theta) + (int)(V7 >= theta);
    int ksc = kcnt;
#pragma unroll
    for (int o = 1; o < 64; o <<= 1) {
        int t2 = __shfl_up(ksc, o, 64);
        ksc += (lane >= o) ? t2 : 0;
    }
    int C = __shfl(ksc, 63, 64);
    int kbase = ksc - kcnt;
    if (C > 128) C = 128;
    unsigned long long* pq = pool[qw];
#define WPOOL(I, VI) if (I < kcnt) { int p = kbase + I; if (p < 128) pq[p] = VI; }
    WPOOL(0, V0) WPOOL(1, V1) WPOOL(2, V2) WPOOL(3, V3)
    WPOOL(4, V4) WPOOL(5, V5) WPOOL(6, V6) WPOOL(7, V7)
#undef WPOOL
    __syncthreads();

    bool h1 = lane < C;
    bool h2 = (lane + 64) < C;
    unsigned long long k1 = h1 ? pq[lane] : 0ull;
    unsigned long long k2 = h2 ? pq[lane + 64] : 0ull;
    int r1 = 0, r2 = 0;
    for (int i = 0; i < C; ++i) {
        unsigned long long ki = pq[i];
        r1 += (int)(ki > k1);
        r2 += (int)(ki > k2);
    }
    unsigned* kout = knn + (size_t)q*20;
    if (h1 && r1 < 20) kout[r1] = 16383u - (unsigned)(k1 & 0x3FFFull);
    if (h2 && r2 < 20) kout[r2] = 16383u - (unsigned)(k2 & 0x3FFFull);
}

// ---------------- kernel 5: fused GEMM + xyz part; G stored in bf16 -----------------
// Round-18 accounting: kgather's 20x512B f32 G-row gathers = 168MB L3 traffic (~45us
// hidden #2). G -> bf16 halves that (error ~1.5e-3 through max-pool, ~+0.01 absmax,
// threshold 0.1675 has 10x headroom). T2 stays f32 (sequential, cheap). kxpart fused
// here (xyz part = 2 small dots per (n,o)) -> one fewer launch.
__global__ __launch_bounds__(256) void kgemm(const float* __restrict__ feat,
                                             const float* __restrict__ wsf,
                                             unsigned short* __restrict__ Gb,
                                             float* __restrict__ T2)
{
    __shared__ float As[32][32];
    __shared__ float Bs[32][128];
    const float* WKC = wsf + OFF_WKC/4;
    const float* CBF = wsf + OFF_CBF/4;
    const int tid = threadIdx.x;
    const int n0 = blockIdx.x * 32;
    const int tx = tid & 15, ty = tid >> 4;
    float acc[2][8] = {};
    for (int kc = 0; kc < 4; ++kc) {
        int c0 = kc * 32;
        for (int i = tid; i < 1024; i += 256) {
            int cl = i >> 5, nl = i & 31;
            As[cl][nl] = feat[(size_t)(c0 + cl)*NPT + n0 + nl];
        }
        for (int i = tid; i < 4096; i += 256) {
            int cl = i >> 7, ol = i & 127;
            Bs[cl][ol] = WKC[(c0 + cl)*128 + ol];
        }
        __syncthreads();
        for (int cc = 0; cc < 32; ++cc) {
            float av[2], bv[8];
#pragma unroll
            for (int r = 0; r < 2; ++r) av[r] = As[cc][ty*2 + r];
#pragma unroll
            for (int s = 0; s < 8; ++s) bv[s] = Bs[cc][tx*8 + s];
#pragma unroll
            for (int r = 0; r < 2; ++r)
#pragma unroll
                for (int s = 0; s < 8; ++s)
                    acc[r][s] = fmaf(av[r], bv[s], acc[r][s]);
        }
        __syncthreads();
    }
#pragma unroll
    for (int r = 0; r < 2; ++r) {
        int n = n0 + ty*2 + r;
        if (tx < 8) {
            // G feature part, bf16-packed: cols 64 + tx*8 .. +8
            unsigned pk[4];
#pragma unroll
            for (int s = 0; s < 4; ++s)
                pk[s] = (unsigned)f2bf(acc[r][2*s]) | ((unsigned)f2bf(acc[r][2*s+1]) << 16);
            uint4 o4; o4.x = pk[0]; o4.y = pk[1]; o4.z = pk[2]; o4.w = pk[3];
            *(uint4*)(Gb + (size_t)n*128 + 64 + tx*8) = o4;
        } else {
            int ob = (tx - 8)*8;
            float* dst = T2 + (size_t)n*128 + 64 + ob;
#pragma unroll
            for (int s = 0; s < 8; ++s) dst[s] = acc[r][s] + CBF[ob + s];
        }
    }
    // fused xyz part: cols 0..63 of G (bf16) and T2 (f32)
    const float4* pts4 = (const float4*)(wsf + OFF_PTS4/4);
    const float4* WAX4 = (const float4*)(wsf + OFF_WAX/4);
    const float4* WBX4 = (const float4*)(wsf + OFF_WBX/4);
    const float*  CBX  = wsf + OFF_CBX/4;
    const int o = tid & 63;
    float4 A = WAX4[o], B = WBX4[o];
    float cb = CBX[o];
#pragma unroll
    for (int r = 0; r < 8; ++r) {
        int n = n0 + r*4 + (tid >> 6);
        float4 p = pts4[n];
        float gv = fmaf(p.x, A.x, fmaf(p.y, A.y, p.z*A.z));
        float tv = fmaf(p.x, B.x, fmaf(p.y, B.y, fmaf(p.z, B.z, cb)));
        Gb[(size_t)n*128 + o] = f2bf(gv);
        T2[(size_t)n*128 + o] = tv;
    }
}

// ---------------- kernel 7: gather + max-pool + f1/f2 + partials (bf16 G) -----------
__global__ __launch_bounds__(256) void kgather(const float* __restrict__ wsf,
                                               const unsigned* __restrict__ knn,
                                               const unsigned short* __restrict__ Gb,
                                               const float* __restrict__ T2,
                                               const float* __restrict__ wd1,
                                               const float* __restrict__ wd2,
                                               float* __restrict__ F, float* __restrict__ F1,
                                               float* __restrict__ F2, float* __restrict__ SPm,
                                               float* __restrict__ PART)
{
    __shared__ float fsh[32][136];
    __shared__ float w1s[16][136];
    __shared__ float w2s[16][136];
    __shared__ float f1sh[32][16];
    __shared__ float f2p[32][8];
    const int tid = threadIdx.x;
    for (int i = tid; i < 2048; i += 256) {
        int o = i >> 7, cc = i & 127;
        w1s[o][cc] = wd1[i];
        w2s[o][cc] = wd2[i];
    }
    const int nl = tid >> 3, qt = tid & 7;   // 32 rows x 8 channel-groups of 16
    const int n = blockIdx.x*32 + nl;
    const unsigned* ip = knn + (size_t)n*20;
    float acc[16];
#pragma unroll
    for (int e = 0; e < 16; ++e) acc[e] = NEG_INF;
    for (int k = 0; k < 20; ++k) {
        unsigned j = ip[k];
        const uint4* g4 = (const uint4*)(Gb + (size_t)j*128 + qt*16);  // 32B = 16 bf16
        uint4 w0 = g4[0], w1 = g4[1];
        acc[0]  = fmaxf(acc[0],  BF2F_LO(w0.x)); acc[1]  = fmaxf(acc[1],  BF2F_HI(w0.x));
        acc[2]  = fmaxf(acc[2],  BF2F_LO(w0.y)); acc[3]  = fmaxf(acc[3],  BF2F_HI(w0.y));
        acc[4]  = fmaxf(acc[4],  BF2F_LO(w0.z)); acc[5]  = fmaxf(acc[5],  BF2F_HI(w0.z));
        acc[6]  = fmaxf(acc[6],  BF2F_LO(w0.w)); acc[7]  = fmaxf(acc[7],  BF2F_HI(w0.w));
        acc[8]  = fmaxf(acc[8],  BF2F_LO(w1.x)); acc[9]  = fmaxf(acc[9],  BF2F_HI(w1.x));
        acc[10] = fmaxf(acc[10], BF2F_LO(w1.y)); acc[11] = fmaxf(acc[11], BF2F_HI(w1.y));
        acc[12] = fmaxf(acc[12], BF2F_LO(w1.z)); acc[13] = fmaxf(acc[13], BF2F_HI(w1.z));
        acc[14] = fmaxf(acc[14], BF2F_LO(w1.w)); acc[15] = fmaxf(acc[15], BF2F_HI(w1.w));
    }
    const float4* t4 = (const float4*)(T2 + (size_t)n*128 + qt*16);
    float4* fg = (float4*)(F + (size_t)n*128 + qt*16);
    float4* fs = (float4*)&fsh[nl][qt*16];
#pragma unroll
    for (int r = 0; r < 4; ++r) {
        float4 tv = t4[r];
        float4 o4;
        o4.x = fmaxf(acc[r*4+0] + tv.x, 0.f);
        o4.y = fmaxf(acc[r*4+1] + tv.y, 0.f);
        o4.z = fmaxf(acc[r*4+2] + tv.z, 0.f);
        o4.w = fmaxf(acc[r*4+3] + tv.w, 0.f);
        fg[r] = o4; fs[r] = o4;
    }
    __syncthreads();
    float a1[2] = {0,0}, a2[2] = {0,0};
    const int ob = qt*2;
    for (int c4 = 0; c4 < 32; ++c4) {
        float4 fv = ((const float4*)&fsh[nl][0])[c4];
#pragma unroll
        for (int r = 0; r < 2; ++r) {
            float4 wv1 = ((const float4*)&w1s[ob + r][0])[c4];
            float4 wv2 = ((const float4*)&w2s[ob + r][0])[c4];
            a1[r] = fmaf(fv.x, wv1.x, fmaf(fv.y, wv1.y, fmaf(fv.z, wv1.z, fmaf(fv.w, wv1.w, a1[r]))));
            a2[r] = fmaf(fv.x, wv2.x, fmaf(fv.y, wv2.y, fmaf(fv.z, wv2.z, fmaf(fv.w, wv2.w, a2[r]))));
        }
    }
    float s2sum = 0.f;
#pragma unroll
    for (int r = 0; r < 2; ++r) {
        a1[r] = fmaxf(a1[r], 0.f);
        a2[r] = fmaxf(a2[r], 0.f);
        s2sum += a2[r];
        F1[(size_t)n*16 + ob + r] = a1[r];
        F2[(size_t)n*16 + ob + r] = a2[r];
        f1sh[nl][ob + r] = a1[r];
    }
    f2p[nl][qt] = s2sum;
    __syncthreads();
    if (qt == 0) {
        float s = 0.f;
#pragma unroll
        for (int t = 0; t < 8; ++t) s += f2p[nl][t];
        SPm[n] = s * (1.0f/16.0f);
    }
    if (tid < 16) {
        float s = 0.f;
        for (int r = 0; r < 32; ++r) s += f1sh[r][tid];
        PART[blockIdx.x*16 + tid] = s;
    }
}

// ---------------- kernel 8: reduce channel mean (512 partials) ----------------
__global__ __launch_bounds__(64) void kch(const float* __restrict__ PART, float* __restrict__ CH)
{
    const int tid = threadIdx.x;
    if (tid < 16) {
        float s = 0.f;
        for (int b = 0; b < 512; ++b) s += PART[b*16 + tid];
        CH[tid] = s * (1.0f/16384.0f);
    }
}

// ---------------- kernel 9: final head + mish + transpose (4 thr/point) -------------
__global__ __launch_bounds__(256) void kfinal(const float* __restrict__ wsf,
                                              const float* __restrict__ F,
                                              const float* __restrict__ F1,
                                              const float* __restrict__ F2,
                                              const float* __restrict__ SPm,
                                              const float* __restrict__ CH,
                                              float* __restrict__ out)
{
    const float* WUP = wsf + OFF_WUP/4;
    const float* BUP = wsf + OFF_BUP/4;
    const int tid = threadIdx.x;
    const int nl = tid >> 2, qt = tid & 3;
    const int n = blockIdx.x*64 + nl;
    float spv = SPm[n];
    float fin[16];
    const float4* f14 = (const float4*)(F1 + (size_t)n*16);
    const float4* f24 = (const float4*)(F2 + (size_t)n*16);
#pragma unroll
    for (int c4 = 0; c4 < 4; ++c4) {
        float4 a = f14[c4], b = f24[c4];
        fin[c4*4+0] = sqrtf(fmaf(CH[c4*4+0], spv, 1e-12f)) + a.x + b.x;
        fin[c4*4+1] = sqrtf(fmaf(CH[c4*4+1], spv, 1e-12f)) + a.y + b.y;
        fin[c4*4+2] = sqrtf(fmaf(CH[c4*4+2], spv, 1e-12f)) + a.z + b.z;
        fin[c4*4+3] = sqrtf(fmaf(CH[c4*4+3], spv, 1e-12f)) + a.w + b.w;
    }
    const float4* fF = (const float4*)(F + (size_t)n*128);
    for (int o4 = qt*8; o4 < qt*8 + 8; ++o4) {
        float4 fv = fF[o4];
        float fa[4] = {fv.x, fv.y, fv.z, fv.w};
#pragma unroll
        for (int e = 0; e < 4; ++e) {
            int o = o4*4 + e;
            float u = BUP[o];
#pragma unroll
            for (int c = 0; c < 16; ++c) u = fmaf(fin[c], WUP[o*16 + c], u);
            u = fmaxf(u, 0.f);
            float fl = fa[e] - u;
            float flc = fminf(fl, 15.f);
            float t = expf(flc);
            float w = 1.f + t;
            float w2 = w*w;
            float th = (w2 - 1.f) / (w2 + 1.f);
            float res = (fl > 15.f) ? fl : fl * th;
            out[(size_t)o*NPT + n] = res;
        }
    }
}

extern "C" void kernel_launch(void* const* d_in, const int* in_sizes, int n_in,
                              void* d_out, int out_size, void* d_ws, size_t ws_size,
                              hipStream_t stream) {
    const float* xyz  = (const float*)d_in[0];
    const float* feat = (const float*)d_in[1];
    const float* w1   = (const float*)d_in[2];
    const float* b1   = (const float*)d_in[3];
    const float* g1   = (const float*)d_in[4];
    const float* bb1  = (const float*)d_in[5];
    const float* m1   = (const float*)d_in[6];
    const float* v1   = (const float*)d_in[7];
    const float* w2   = (const float*)d_in[8];
    const float* b2   = (const float*)d_in[9];
    const float* g2   = (const float*)d_in[10];
    const float* bb2  = (const float*)d_in[11];
    const float* m2   = (const float*)d_in[12];
    const float* v2   = (const float*)d_in[13];
    const float* wd1  = (const float*)d_in[14];
    const float* wd2  = (const float*)d_in[15];
    const float* wup  = (const float*)d_in[16];
    const float* bup  = (const float*)d_in[17];
    const float* gu   = (const float*)d_in[18];
    const float* bu2  = (const float*)d_in[19];
    const float* mu   = (const float*)d_in[20];
    const float* vu   = (const float*)d_in[21];
    float* out = (float*)d_out;

    float* wsf = (float*)d_ws;
    unsigned* bm   = (unsigned*)((char*)d_ws + OFF_R);
    unsigned* knn  = (unsigned*)((char*)d_ws + OFF_KNN);
    float* TAU  = (float*)((char*)d_ws + OFF_TAU);
    float* PART = (float*)((char*)d_ws + OFF_TAU);   // TAU region dead after kpush
    float* CH   = (float*)((char*)d_ws + OFF_CH);
    // region R reused after ksel: Gb bf16 (4MB), then f32 arrays
    unsigned short* Gb = (unsigned short*)((char*)d_ws + OFF_R);
    float* T2 = (float*)((char*)d_ws + OFF_R + 4194304);
    float* F  = T2 + 2097152;
    float* F1 = F  + 2097152;
    float* F2 = F1 + 262144;
    float* SPm = F2 + 262144;

    kprep<<<dim3(65),  dim3(256), 0, stream>>>(xyz, w1,b1,g1,bb1,m1,v1,
                                               w2,b2,g2,bb2,m2,v2,
                                               wup,bup,gu,bu2,mu,vu, wsf);
    ktau <<<dim3(512), dim3(256), 0, stream>>>(wsf, TAU);
    kpush<<<dim3(2048), dim3(256), 0, stream>>>(wsf, TAU, bm);
    ksel <<<dim3(4096), dim3(256), 0, stream>>>(wsf, bm, knn);
    kgemm<<<dim3(512), dim3(256), 0, stream>>>(feat, wsf, Gb, T2);
    kgather<<<dim3(512), dim3(256), 0, stream>>>(wsf, knn, Gb, T2, wd1, wd2, F, F1, F2, SPm, PART);
    kch  <<<dim3(1),   dim3(64), 0, stream>>>(PART, CH);
    kfinal<<<dim3(256), dim3(256), 0, stream>>>(wsf, F, F1, F2, SPm, CH, out);
}